// Round 8
// baseline (168.994 us; speedup 1.0000x reference)
//
#include <hip/hip_runtime.h>

// ---------------------------------------------------------------------------
// Fused equivariant NLMP, MI355X.
// Main kernel: one-shot blocks (1 batch of 64 edges each); wave = output
// column j; lane = edge. Weights read via VMEM (uniform address -> L1
// broadcast), per-edge data via LDS (each TP u-step one ds_read_b128).
// CSR rank placement + streaming gather. 3-barrier parallel scan.
// ---------------------------------------------------------------------------

#define EPB   64
#define BLOCK 512
#define NNP   10240

#define SQRT3_F      1.7320508075688772f
#define INV_SQRT3_F  0.5773502691896258f
#define INV_SQRT10_F 0.31622776601683794f
#define A1_4         0.044194173824159216f   // (1/sqrt(32)) * (1/4)
#define A2_4         0.0625f                 // (1/sqrt(16)) * (1/4)

typedef _Float16 f16;
typedef f16 f16x2 __attribute__((ext_vector_type(2)));
typedef f16 f16x4 __attribute__((ext_vector_type(4)));
typedef f16 f16x8 __attribute__((ext_vector_type(8)));

__global__ void zero_f32(float* __restrict__ p, int n) {
    int i = blockIdx.x * blockDim.x + threadIdx.x;
    if (i < n) p[i] = 0.0f;
}

// fused: zero counts + convert weights to fp16 (u,j)-grouped layout with
// path constants folded in.
__global__ void prep(const float* __restrict__ W2, const float* __restrict__ W4,
                     f16* __restrict__ W2h, f16* __restrict__ W4h,
                     int* __restrict__ counts, int NN) {
    int gid = blockIdx.x * blockDim.x + threadIdx.x;
    if (gid < NN) counts[gid] = 0;
    if (gid >= NNP && gid < NNP + 8192) {
        int idx = gid - NNP;
        int q = idx >> 4, h = idx & 15;
        int u = (q & 127) >> 3, j = q & 7, p = q >> 7;
        float sc = (p == 1) ? (A1_4 * INV_SQRT3_F) : A1_4;
        W2h[(((u * 8 + j) * 4) + p) * 16 + h] = (f16)(W2[h * 512 + q] * sc);
    } else if (gid >= NNP + 8192 && gid < NNP + 8192 + 6144) {
        int idx = gid - NNP - 8192;
        int q = idx >> 4, h = idx & 15;
        int p = q >> 6, r = q & 63;
        int u = r >> 3, j = r & 7;
        float sc = (p == 1 || p == 3) ? (A2_4 * INV_SQRT3_F) : A2_4;
        W4h[(((u * 8 + j) * 6) + p) * 16 + h] = (f16)(W4[h * 384 + q] * sc);
    }
}

__global__ void hist_rank(const int* __restrict__ edst, int* __restrict__ counts,
                          int* __restrict__ rank, int E) {
    int e = blockIdx.x * blockDim.x + threadIdx.x;
    if (e < E) rank[e] = atomicAdd(&counts[edst[e]], 1);
}

// single-block scan, CH elems/thread, two passes, 3 barriers
__global__ void scan_offsets(const int* __restrict__ counts, int* __restrict__ offsets, int nn) {
    __shared__ int wbase[16];
    const int tid = threadIdx.x, lane = tid & 63, w = tid >> 6;
    const int CH = (nn + 1023) >> 10;
    int s = 0;
    for (int k = 0; k < CH; ++k) {
        int i = tid * CH + k;
        if (i < nn) s += counts[i];
    }
    int sc = s;
    #pragma unroll
    for (int off = 1; off < 64; off <<= 1) {
        int t = __shfl_up(sc, off, 64);
        if (lane >= off) sc += t;
    }
    if (lane == 63) wbase[w] = sc;
    __syncthreads();
    if (tid < 16) {
        int v = wbase[tid];
        int p = v;
        #pragma unroll
        for (int off = 1; off < 16; off <<= 1) {
            int t = __shfl_up(p, off, 16);
            if (tid >= off) p += t;
        }
        wbase[tid] = p - v;   // exclusive wave base
    }
    __syncthreads();
    int excl = wbase[w] + sc - s;
    for (int k = 0; k < CH; ++k) {
        int i = tid * CH + k;
        if (i < nn) { offsets[i] = excl; excl += counts[i]; }
    }
}

__global__ void gather_out(const float* __restrict__ eout, const int* __restrict__ offsets,
                           const int* __restrict__ counts, float* __restrict__ out, int nn) {
    const int tid = threadIdx.x;
    const int n = blockIdx.x * 8 + (tid >> 5);
    const int t = tid & 31;
    if (n >= nn) return;
    const int beg = offsets[n];
    const int cnt = counts[n];
    float a0 = 0.0f, a1 = 0.0f, a2 = 0.0f, a3 = 0.0f;
    int k = 0;
    for (; k + 3 < cnt; k += 4) {
        a0 += eout[(size_t)(beg + k) * 32 + t];
        a1 += eout[(size_t)(beg + k + 1) * 32 + t];
        a2 += eout[(size_t)(beg + k + 2) * 32 + t];
        a3 += eout[(size_t)(beg + k + 3) * 32 + t];
    }
    for (; k < cnt; ++k) a0 += eout[(size_t)(beg + k) * 32 + t];
    out[(size_t)n * 32 + t] = (a0 + a1) + (a2 + a3);
}

static __device__ __forceinline__ float dot16h(const f16x2* __restrict__ hh,
                                               const f16* __restrict__ w) {
    union U { f16x8 v; f16x2 p[4]; };
    U a, b;
    a.v = *(const f16x8*)(w);
    b.v = *(const f16x8*)(w + 8);
    float s = 0.0f;
#if __has_builtin(__builtin_amdgcn_fdot2)
    s = __builtin_amdgcn_fdot2(hh[0], a.p[0], s, false);
    s = __builtin_amdgcn_fdot2(hh[1], a.p[1], s, false);
    s = __builtin_amdgcn_fdot2(hh[2], a.p[2], s, false);
    s = __builtin_amdgcn_fdot2(hh[3], a.p[3], s, false);
    s = __builtin_amdgcn_fdot2(hh[4], b.p[0], s, false);
    s = __builtin_amdgcn_fdot2(hh[5], b.p[1], s, false);
    s = __builtin_amdgcn_fdot2(hh[6], b.p[2], s, false);
    s = __builtin_amdgcn_fdot2(hh[7], b.p[3], s, false);
#else
    #pragma unroll
    for (int i = 0; i < 4; ++i) {
        s += (float)hh[i][0]   * (float)a.p[i][0] + (float)hh[i][1]   * (float)a.p[i][1];
        s += (float)hh[i+4][0] * (float)b.p[i][0] + (float)hh[i+4][1] * (float)b.p[i][1];
    }
#endif
    return s;
}

static __device__ __forceinline__ float tanh_fast(float x) {
    x = fminf(fmaxf(x, -15.0f), 15.0f);
    float e = __expf(2.0f * x);
    return (e - 1.0f) * __builtin_amdgcn_rcpf(e + 1.0f);
}

// ATOMIC=0: write edge line to eout[pos[e]]; ATOMIC=1: atomicAdd into out[N][32]
template <int ATOMIC>
__global__ void __launch_bounds__(BLOCK, 8) eq_nlmp(
    const float* __restrict__ x,        // [N,32]
    const int*   __restrict__ esrc,     // [E]
    const int*   __restrict__ edst,     // [E]
    const float* __restrict__ evec,     // [E,3]
    const float* __restrict__ emb,      // [E,10]
    const float* __restrict__ nrm,      // [E]
    const float* __restrict__ W1,       // [10,16] fp32
    const float* __restrict__ W3,       // [10,16] fp32
    const f16*   __restrict__ W2h,
    const f16*   __restrict__ W4h,
    const int*   __restrict__ offsets,
    const int*   __restrict__ rank,
    float*       __restrict__ dst_buf,
    int E)
{
    __shared__ float sXP  [EPB * 68];   // per edge u=0..15: [su,a0,a1,a2]; reused as sOUT
    __shared__ float sSTVT[EPB * 36];   // per edge u=0..7: [st,vt0,vt1,vt2]
    __shared__ float sEM  [EPB * 12];
    __shared__ float sSH  [EPB * 3];
    __shared__ f16   sH1  [EPB * 20];
    __shared__ f16   sH2  [EPB * 20];
    __shared__ float sW1t [16 * 12];    // transposed [hid][i]
    __shared__ float sW3t [16 * 12];
    __shared__ int   sPOS [EPB];
    __shared__ int   sDST [EPB];
    __shared__ float sNRM [EPB];

    const int tid = threadIdx.x;
    const int e   = tid >> 3;
    const int q   = tid & 7;
    const int l   = tid & 63;
    const int js  = tid >> 6;   // kept in VGPR on purpose: weight reads go VMEM
                                // (uniform addr -> one L1 txn broadcast), NOT SMEM
                                // (SMEM shares lgkmcnt with ds_read, returns OOO,
                                // forces lgkmcnt(0) serialization per u-step).

    const int ge0 = blockIdx.x * EPB;
    int ge = ge0 + e;
    const int nvalid = (E - ge0 < EPB) ? (E - ge0) : EPB;
    if (ge >= E) ge = E - 1;

    if (tid < 160) {
        const int row = tid >> 4, hid = tid & 15;   // W1[row][hid]
        sW1t[hid * 12 + row] = W1[tid];
        sW3t[hid * 12 + row] = W3[tid];
    }

    // ---- prelude: gather + repack per-edge data ----
    {
        const int src = esrc[ge];
        const int dst = edst[ge];
        const float4* xs4 = (const float4*)(x + (size_t)src * 32);
        const float4* xd4 = (const float4*)(x + (size_t)dst * 32);
        float4 a = xs4[q], bq = xd4[q];
        float av[4] = {a.x, a.y, a.z, a.w};
        float bv[4] = {bq.x, bq.y, bq.z, bq.w};
        #pragma unroll
        for (int m = 0; m < 4; ++m) {
            const int i = 4 * q + m;
            {
                int pos;
                if (i < 8) pos = 4 * i;
                else { int r = i - 8; int u = (r * 2731) >> 13; pos = 4 * u + 1 + (r - 3 * u); }
                sXP[e * 68 + pos] = av[m];
            }
            {
                int pos;
                if (i < 8) pos = 4 * (8 + i);
                else { int r = i - 8; int u = (r * 2731) >> 13; pos = 4 * (8 + u) + 1 + (r - 3 * u); }
                sXP[e * 68 + pos] = bv[m];
            }
        }
        if (q < 5) {
            float2 t = *(const float2*)(emb + (size_t)ge * 10 + 2 * q);
            sEM[e * 12 + 2 * q]     = t.x;
            sEM[e * 12 + 2 * q + 1] = t.y;
        }
        if (q == 0) {
            float vx = evec[(size_t)ge * 3 + 0];
            float vy = evec[(size_t)ge * 3 + 1];
            float vz = evec[(size_t)ge * 3 + 2];
            float rn = sqrtf(vx * vx + vy * vy + vz * vz);
            sSH[e * 3 + 0] = SQRT3_F * vx / rn;
            sSH[e * 3 + 1] = SQRT3_F * vy / rn;
            sSH[e * 3 + 2] = SQRT3_F * vz / rn;
        }
        if (q == 1) sNRM[e] = nrm[ge];
        if (q == 2) {
            if (ATOMIC) sDST[e] = dst;
            else        sPOS[e] = offsets[dst] + rank[ge];
        }
    }
    __syncthreads();

    // ---- MLP1 + MLP2: thread (e,q) computes hid = q, q+8 for both ----
    {
        float2 em0 = *(const float2*)&sEM[e * 12 + 0];
        float2 em1 = *(const float2*)&sEM[e * 12 + 2];
        float2 em2 = *(const float2*)&sEM[e * 12 + 4];
        float2 em3 = *(const float2*)&sEM[e * 12 + 6];
        float2 em4 = *(const float2*)&sEM[e * 12 + 8];
        #pragma unroll
        for (int t = 0; t < 2; ++t) {
            const int hid = q + 8 * t;
            {
                const float4 wa = *(const float4*)&sW1t[hid * 12 + 0];
                const float4 wb = *(const float4*)&sW1t[hid * 12 + 4];
                const float2 wc = *(const float2*)&sW1t[hid * 12 + 8];
                float acc = em0.x*wa.x + em0.y*wa.y + em1.x*wa.z + em1.y*wa.w
                          + em2.x*wb.x + em2.y*wb.y + em3.x*wb.z + em3.y*wb.w
                          + em4.x*wc.x + em4.y*wc.y;
                sH1[e * 20 + hid] = (f16)fmaxf(acc * INV_SQRT10_F, 0.0f);
            }
            {
                const float4 wa = *(const float4*)&sW3t[hid * 12 + 0];
                const float4 wb = *(const float4*)&sW3t[hid * 12 + 4];
                const float2 wc = *(const float2*)&sW3t[hid * 12 + 8];
                float acc = em0.x*wa.x + em0.y*wa.y + em1.x*wa.z + em1.y*wa.w
                          + em2.x*wb.x + em2.y*wb.y + em3.x*wb.z + em3.y*wb.w
                          + em4.x*wc.x + em4.y*wc.y;
                sH2[e * 20 + hid] = (f16)fmaxf(acc * INV_SQRT10_F, 0.0f);
            }
        }
    }
    __syncthreads();

    const float sh0 = sSH[l * 3 + 0], sh1 = sSH[l * 3 + 1], sh2 = sSH[l * 3 + 2];

    union HU { f16x4 q4[4]; f16x2 p[8]; };
    HU H;
    #pragma unroll
    for (int k = 0; k < 4; ++k) H.q4[k] = *(const f16x4*)&sH1[l * 20 + 4 * k];

    // ---- TP1 (a1/4 and 1/sqrt3 folded into W2h; weights via VMEM/L1) ----
    const f16* __restrict__ w2base = W2h + (size_t)(js * 4) * 16;
    float sts = 0.0f, svs = 0.0f, vt0 = 0.0f, vt1 = 0.0f, vt2 = 0.0f;
    #pragma unroll 4
    for (int u = 0; u < 16; ++u) {
        const float4 d = *(const float4*)&sXP[l * 68 + 4 * u];   // [su,a0,a1,a2]
        const float vd = d.y * sh0 + d.z * sh1 + d.w * sh2;
        const f16* wb = w2base + (size_t)u * (32 * 16);          // +1KB/step, imm-foldable
        const float wss = dot16h(H.p, wb);
        const float wvv = dot16h(H.p, wb + 16);
        const float wsv = dot16h(H.p, wb + 32);
        const float wvs = dot16h(H.p, wb + 48);
        sts += d.x * wss + vd * wvv;
        svs += d.x * wsv;
        vt0 += d.y * wvs;
        vt1 += d.z * wvs;
        vt2 += d.w * wvs;
    }
    {
        float4 stvt;
        stvt.x = sts;
        stvt.y = svs * sh0 + vt0;
        stvt.z = svs * sh1 + vt1;
        stvt.w = svs * sh2 + vt2;
        *(float4*)&sSTVT[l * 36 + 4 * js] = stvt;
    }
    __syncthreads();

    #pragma unroll
    for (int k = 0; k < 4; ++k) H.q4[k] = *(const f16x4*)&sH2[l * 20 + 4 * k];

    // ---- TP2 (a2/4 and 1/sqrt3 folded into W4h; weights via VMEM/L1) ----
    const f16* __restrict__ w4base = W4h + (size_t)(js * 6) * 16;
    float scal = 0.0f, gat = 0.0f, csv = 0.0f, vv0 = 0.0f, vv1 = 0.0f, vv2 = 0.0f;
    #pragma unroll 4
    for (int u = 0; u < 8; ++u) {
        const float4 d = *(const float4*)&sSTVT[l * 36 + 4 * u];  // [st,vt0,vt1,vt2]
        const float vd = d.y * sh0 + d.z * sh1 + d.w * sh2;
        const f16* wb = w4base + (size_t)u * (48 * 16);           // +1.5KB/step
        const float wA  = dot16h(H.p, wb);
        const float wAv = dot16h(H.p, wb + 16);
        const float wB  = dot16h(H.p, wb + 32);
        const float wBv = dot16h(H.p, wb + 48);
        const float wC  = dot16h(H.p, wb + 64);
        const float wCv = dot16h(H.p, wb + 80);
        scal += d.x * wA + vd * wAv;
        gat  += d.x * wB + vd * wBv;
        csv  += d.x * wC;
        vv0  += d.y * wCv;
        vv1  += d.z * wCv;
        vv2  += d.w * wCv;
    }
    const float ve0 = csv * sh0 + vv0;
    const float ve1 = csv * sh1 + vv1;
    const float ve2 = csv * sh2 + vv2;

    const float nn = sNRM[l];
    const float ts = tanh_fast(scal) * nn;
    const float tg = tanh_fast(gat) * nn;

    if (ATOMIC) {
        if (l < nvalid) {
            float* ob = dst_buf + (size_t)sDST[l] * 32;
            atomicAdd(ob + js,             ts);
            atomicAdd(ob + 8 + 3 * js + 0, ve0 * tg);
            atomicAdd(ob + 8 + 3 * js + 1, ve1 * tg);
            atomicAdd(ob + 8 + 3 * js + 2, ve2 * tg);
        }
    } else {
        // stage outputs into sXP (all TP1 reads completed before STVT barrier)
        float* sOUT = sXP;
        sOUT[l * 68 + js]             = ts;
        sOUT[l * 68 + 8 + 3 * js + 0] = ve0 * tg;
        sOUT[l * 68 + 8 + 3 * js + 1] = ve1 * tg;
        sOUT[l * 68 + 8 + 3 * js + 2] = ve2 * tg;
        __syncthreads();
        if (e < nvalid) {
            float4 v = *(const float4*)&sOUT[e * 68 + 4 * q];
            *(float4*)&dst_buf[(size_t)sPOS[e] * 32 + 4 * q] = v;
        }
    }
}

extern "C" void kernel_launch(void* const* d_in, const int* in_sizes, int n_in,
                              void* d_out, int out_size, void* d_ws, size_t ws_size,
                              hipStream_t stream) {
    const float* x    = (const float*)d_in[0];
    const int*   esrc = (const int*)  d_in[1];
    const int*   edst = (const int*)  d_in[2];
    const float* evec = (const float*)d_in[3];
    const float* emb  = (const float*)d_in[4];
    const float* nrm  = (const float*)d_in[5];
    const float* W1   = (const float*)d_in[7];
    const float* W2   = (const float*)d_in[8];
    const float* W3   = (const float*)d_in[9];
    const float* W4   = (const float*)d_in[10];
    float* out = (float*)d_out;

    const int E  = in_sizes[1];
    const int NN = out_size / 32;
    const int nbatch = (E + EPB - 1) / EPB;

    size_t o_w2h   = 0;
    size_t o_w4h   = o_w2h + 512 * 16 * 2;
    size_t o_cnt   = o_w4h + 384 * 16 * 2;
    size_t o_off   = o_cnt + (size_t)NNP * 4;
    size_t o_rank  = o_off + (size_t)NNP * 4;
    size_t o_eout  = (o_rank + (size_t)E * 4 + 255) & ~(size_t)255;
    size_t need    = o_eout + (size_t)E * 128;

    char* ws = (char*)d_ws;
    f16* W2h = (f16*)(ws + o_w2h);
    f16* W4h = (f16*)(ws + o_w4h);
    int*   counts  = (int*)  (ws + o_cnt);
    int*   offsets = (int*)  (ws + o_off);
    int*   rank    = (int*)  (ws + o_rank);
    float* eout    = (float*)(ws + o_eout);

    const int prep_threads = NNP + 8192 + 6144;
    prep<<<(prep_threads + 255) / 256, 256, 0, stream>>>(W2, W4, W2h, W4h, counts, NN);

    if (NN <= NNP && ws_size >= need) {
        hist_rank<<<(E + 255) / 256, 256, 0, stream>>>(edst, counts, rank, E);
        scan_offsets<<<1, 1024, 0, stream>>>(counts, offsets, NN);
        eq_nlmp<0><<<nbatch, BLOCK, 0, stream>>>(x, esrc, edst, evec, emb, nrm,
                                                 W1, W3, W2h, W4h, offsets, rank, eout, E);
        gather_out<<<(NN + 7) / 8, 256, 0, stream>>>(eout, offsets, counts, out, NN);
    } else {
        zero_f32<<<(out_size + 255) / 256, 256, 0, stream>>>(out, out_size);
        eq_nlmp<1><<<nbatch, BLOCK, 0, stream>>>(x, esrc, edst, evec, emb, nrm,
                                                 W1, W3, W2h, W4h, nullptr, nullptr, out, E);
    }
}

// Round 9
// 91.555 us; speedup vs baseline: 1.8458x; 1.8458x over previous
//
#include <hip/hip_runtime.h>

// ---------------------------------------------------------------------------
// Fused equivariant NLMP, MI355X — MFMA edition.
// Per 32-edge block: w = H[32,16] @ W2sigma[16,512] via v_mfma_f32_16x16x16f16
// (A = sigma-permuted fp16 weights from global/L1, B = per-edge h from LDS,
//  C written to LDS as fp16 b64 per tile). Contraction reads per-(u,j) path
// groups as one b64/b128. CSR rank placement + streaming gather unchanged.
// ---------------------------------------------------------------------------

#define EPB   32
#define BLOCK 256
#define NNP   10240

#define SQRT3_F      1.7320508075688772f
#define INV_SQRT3_F  0.5773502691896258f
#define INV_SQRT10_F 0.31622776601683794f
#define A1_4         0.044194173824159216f   // (1/sqrt(32)) * (1/4)
#define A2_4         0.0625f                 // (1/sqrt(16)) * (1/4)

#define SWSTRIDE 1040                        // bytes per edge row in sW (16|1040, 8|1040)

typedef _Float16 f16;
typedef f16 f16x2 __attribute__((ext_vector_type(2)));
typedef f16 f16x4 __attribute__((ext_vector_type(4)));
typedef f16 f16x8 __attribute__((ext_vector_type(8)));
typedef float f32x4v __attribute__((ext_vector_type(4)));

#if __has_builtin(__builtin_amdgcn_mfma_f32_16x16x16f16)
#define MFMA16(a, b, c) __builtin_amdgcn_mfma_f32_16x16x16f16((a), (b), (c), 0, 0, 0)
#define HAVE_MFMA16 1
#elif __has_builtin(__builtin_amdgcn_mfma_f32_16x16x16_f16)
#define MFMA16(a, b, c) __builtin_amdgcn_mfma_f32_16x16x16_f16((a), (b), (c), 0, 0, 0)
#define HAVE_MFMA16 1
#else
#define HAVE_MFMA16 0
#endif

__global__ void zero_f32(float* __restrict__ p, int n) {
    int i = blockIdx.x * blockDim.x + threadIdx.x;
    if (i < n) p[i] = 0.0f;
}

// fused: zero counts + build sigma-permuted fp16 weight matrices.
// W2s[r][h], r=(u8j)*4+p, q=p*128+(r>>2), p<4           (512x16)
// W4s[r][h], r=(u8j)*8+p, q=p*64+(r>>3), p<6, pad p>=6  (512x16)
__global__ void prep(const float* __restrict__ W2, const float* __restrict__ W4,
                     f16* __restrict__ W2s, f16* __restrict__ W4s,
                     int* __restrict__ counts, int NN) {
    int gid = blockIdx.x * blockDim.x + threadIdx.x;
    if (gid < NN) counts[gid] = 0;
    if (gid >= NNP && gid < NNP + 8192) {
        int idx = gid - NNP;
        int r = idx >> 4, h = idx & 15;
        int p = r & 3;
        int q = p * 128 + (r >> 2);
        float sc = (p == 1) ? (A1_4 * INV_SQRT3_F) : A1_4;
        W2s[r * 16 + h] = (f16)(W2[h * 512 + q] * sc);
    } else if (gid >= NNP + 8192 && gid < NNP + 16384) {
        int idx = gid - NNP - 8192;
        int r = idx >> 4, h = idx & 15;
        int p = r & 7;
        if (p < 6) {
            int q = p * 64 + (r >> 3);
            float sc = (p == 1 || p == 3) ? (A2_4 * INV_SQRT3_F) : A2_4;
            W4s[r * 16 + h] = (f16)(W4[h * 384 + q] * sc);
        } else {
            W4s[r * 16 + h] = (f16)0.0f;
        }
    }
}

__global__ void hist_rank(const int* __restrict__ edst, int* __restrict__ counts,
                          int* __restrict__ rank, int E) {
    int e = blockIdx.x * blockDim.x + threadIdx.x;
    if (e < E) rank[e] = atomicAdd(&counts[edst[e]], 1);
}

// single-block scan, CH elems/thread, two passes, 3 barriers
__global__ void scan_offsets(const int* __restrict__ counts, int* __restrict__ offsets, int nn) {
    __shared__ int wbase[16];
    const int tid = threadIdx.x, lane = tid & 63, w = tid >> 6;
    const int CH = (nn + 1023) >> 10;
    int s = 0;
    for (int k = 0; k < CH; ++k) {
        int i = tid * CH + k;
        if (i < nn) s += counts[i];
    }
    int sc = s;
    #pragma unroll
    for (int off = 1; off < 64; off <<= 1) {
        int t = __shfl_up(sc, off, 64);
        if (lane >= off) sc += t;
    }
    if (lane == 63) wbase[w] = sc;
    __syncthreads();
    if (tid < 16) {
        int v = wbase[tid];
        int p = v;
        #pragma unroll
        for (int off = 1; off < 16; off <<= 1) {
            int t = __shfl_up(p, off, 16);
            if (tid >= off) p += t;
        }
        wbase[tid] = p - v;
    }
    __syncthreads();
    int excl = wbase[w] + sc - s;
    for (int k = 0; k < CH; ++k) {
        int i = tid * CH + k;
        if (i < nn) { offsets[i] = excl; excl += counts[i]; }
    }
}

__global__ void gather_out(const float* __restrict__ eout, const int* __restrict__ offsets,
                           const int* __restrict__ counts, float* __restrict__ out, int nn) {
    const int tid = threadIdx.x;
    const int n = blockIdx.x * 8 + (tid >> 5);
    const int t = tid & 31;
    if (n >= nn) return;
    const int beg = offsets[n];
    const int cnt = counts[n];
    float a0 = 0.0f, a1 = 0.0f, a2 = 0.0f, a3 = 0.0f;
    int k = 0;
    for (; k + 3 < cnt; k += 4) {
        a0 += eout[(size_t)(beg + k) * 32 + t];
        a1 += eout[(size_t)(beg + k + 1) * 32 + t];
        a2 += eout[(size_t)(beg + k + 2) * 32 + t];
        a3 += eout[(size_t)(beg + k + 3) * 32 + t];
    }
    for (; k < cnt; ++k) a0 += eout[(size_t)(beg + k) * 32 + t];
    out[(size_t)n * 32 + t] = (a0 + a1) + (a2 + a3);
}

static __device__ __forceinline__ float tanh_fast(float x) {
    x = fminf(fmaxf(x, -15.0f), 15.0f);
    float e = __expf(2.0f * x);
    return (e - 1.0f) * __builtin_amdgcn_rcpf(e + 1.0f);
}

// ATOMIC=0: write edge line to eout[pos[e]]; ATOMIC=1: atomicAdd into out[N][32]
template <int ATOMIC>
__global__ void __launch_bounds__(BLOCK, 3) eq_nlmp(
    const float* __restrict__ x,        // [N,32]
    const int*   __restrict__ esrc,     // [E]
    const int*   __restrict__ edst,     // [E]
    const float* __restrict__ evec,     // [E,3]
    const float* __restrict__ emb,      // [E,10]
    const float* __restrict__ nrm,      // [E]
    const float* __restrict__ W1,       // [10,16] fp32
    const float* __restrict__ W3,       // [10,16] fp32
    const f16*   __restrict__ W2s,      // sigma layout [512][16]
    const f16*   __restrict__ W4s,      // sigma layout [512][16]
    const int*   __restrict__ offsets,
    const int*   __restrict__ rank,
    float*       __restrict__ dst_buf,
    int E)
{
    __shared__ __align__(16) char  sWraw[EPB * SWSTRIDE];  // per-edge w (fp16, sigma order)
    __shared__ float sXP  [EPB * 68];   // per edge u: [su,a0,a1,a2]; reused as sOUT
    __shared__ float sSTVT[EPB * 36];
    __shared__ float sEM  [EPB * 12];
    __shared__ float sSH  [EPB * 3];
    __shared__ f16   sH1  [EPB * 16];   // [e][h] row-major
    __shared__ f16   sH2  [EPB * 16];
    __shared__ float sW1t [16 * 12];
    __shared__ float sW3t [16 * 12];
    __shared__ int   sPOS [EPB];
    __shared__ int   sDST [EPB];
    __shared__ float sNRM [EPB];

    const int tid = threadIdx.x;
    const int e   = tid >> 3;   // prelude/MLP/store role: edge 0..31
    const int q   = tid & 7;

    const int ge0 = blockIdx.x * EPB;
    int ge = ge0 + e;
    const int nvalid = (E - ge0 < EPB) ? (E - ge0) : EPB;
    if (ge >= E) ge = E - 1;

    if (tid < 160) {
        const int row = tid >> 4, hid = tid & 15;
        sW1t[hid * 12 + row] = W1[tid];
        sW3t[hid * 12 + row] = W3[tid];
    }

    // ---- prelude: gather + repack per-edge data ----
    {
        const int src = esrc[ge];
        const int dst = edst[ge];
        const float4* xs4 = (const float4*)(x + (size_t)src * 32);
        const float4* xd4 = (const float4*)(x + (size_t)dst * 32);
        float4 a = xs4[q], bq = xd4[q];
        float av[4] = {a.x, a.y, a.z, a.w};
        float bv[4] = {bq.x, bq.y, bq.z, bq.w};
        #pragma unroll
        for (int m = 0; m < 4; ++m) {
            const int i = 4 * q + m;
            {
                int pos;
                if (i < 8) pos = 4 * i;
                else { int r = i - 8; int u = (r * 2731) >> 13; pos = 4 * u + 1 + (r - 3 * u); }
                sXP[e * 68 + pos] = av[m];
            }
            {
                int pos;
                if (i < 8) pos = 4 * (8 + i);
                else { int r = i - 8; int u = (r * 2731) >> 13; pos = 4 * (8 + u) + 1 + (r - 3 * u); }
                sXP[e * 68 + pos] = bv[m];
            }
        }
        if (q < 5) {
            float2 t = *(const float2*)(emb + (size_t)ge * 10 + 2 * q);
            sEM[e * 12 + 2 * q]     = t.x;
            sEM[e * 12 + 2 * q + 1] = t.y;
        }
        if (q == 0) {
            float vx = evec[(size_t)ge * 3 + 0];
            float vy = evec[(size_t)ge * 3 + 1];
            float vz = evec[(size_t)ge * 3 + 2];
            float rn = sqrtf(vx * vx + vy * vy + vz * vz);
            sSH[e * 3 + 0] = SQRT3_F * vx / rn;
            sSH[e * 3 + 1] = SQRT3_F * vy / rn;
            sSH[e * 3 + 2] = SQRT3_F * vz / rn;
        }
        if (q == 1) sNRM[e] = nrm[ge];
        if (q == 2) {
            if (ATOMIC) sDST[e] = dst;
            else        sPOS[e] = offsets[dst] + rank[ge];
        }
    }
    __syncthreads();

    // ---- MLP1 + MLP2: thread (e,q) computes hid = q, q+8 for both ----
    {
        float2 em0 = *(const float2*)&sEM[e * 12 + 0];
        float2 em1 = *(const float2*)&sEM[e * 12 + 2];
        float2 em2 = *(const float2*)&sEM[e * 12 + 4];
        float2 em3 = *(const float2*)&sEM[e * 12 + 6];
        float2 em4 = *(const float2*)&sEM[e * 12 + 8];
        #pragma unroll
        for (int t = 0; t < 2; ++t) {
            const int hid = q + 8 * t;
            {
                const float4 wa = *(const float4*)&sW1t[hid * 12 + 0];
                const float4 wb = *(const float4*)&sW1t[hid * 12 + 4];
                const float2 wc = *(const float2*)&sW1t[hid * 12 + 8];
                float acc = em0.x*wa.x + em0.y*wa.y + em1.x*wa.z + em1.y*wa.w
                          + em2.x*wb.x + em2.y*wb.y + em3.x*wb.z + em3.y*wb.w
                          + em4.x*wc.x + em4.y*wc.y;
                sH1[e * 16 + hid] = (f16)fmaxf(acc * INV_SQRT10_F, 0.0f);
            }
            {
                const float4 wa = *(const float4*)&sW3t[hid * 12 + 0];
                const float4 wb = *(const float4*)&sW3t[hid * 12 + 4];
                const float2 wc = *(const float2*)&sW3t[hid * 12 + 8];
                float acc = em0.x*wa.x + em0.y*wa.y + em1.x*wa.z + em1.y*wa.w
                          + em2.x*wb.x + em2.y*wb.y + em3.x*wb.z + em3.y*wb.w
                          + em4.x*wc.x + em4.y*wc.y;
                sH2[e * 16 + hid] = (f16)fmaxf(acc * INV_SQRT10_F, 0.0f);
            }
        }
    }
    __syncthreads();

    // ---- MFMA roles ----
    const int l   = tid & 63;
    const int wv  = tid >> 6;     // wave 0..3
    const int et  = wv & 1;       // edge-tile 0..1
    const int qh  = wv >> 1;      // sigma-row half 0..1
    const int m16 = l & 15;
    const int g4  = (l >> 4) << 2;
    char* sWB = sWraw;

    // ---- MFMA phase 1: w1 = W2s[512,16] @ H1^T[16,32] -> sW fp16 ----
    {
#if HAVE_MFMA16
        f16x4 bf = *(const f16x4*)&sH1[(et * 16 + m16) * 16 + g4];
        #pragma unroll
        for (int t = 0; t < 16; ++t) {
            const int qt = qh * 16 + t;
            f16x4 af = *(const f16x4*)(W2s + (qt * 16 + m16) * 16 + g4);
            f32x4v acc = (f32x4v){0.0f, 0.0f, 0.0f, 0.0f};
            acc = MFMA16(af, bf, acc);
            f16x4 hv;
            hv[0] = (f16)acc[0]; hv[1] = (f16)acc[1];
            hv[2] = (f16)acc[2]; hv[3] = (f16)acc[3];
            *(f16x4*)(sWB + (et * 16 + m16) * SWSTRIDE + (qt * 16 + g4) * 2) = hv;
        }
#else
        // correctness fallback: each lane computes its C fragment serially
        #pragma unroll 2
        for (int t = 0; t < 16; ++t) {
            const int qt = qh * 16 + t;
            f16x4 hv;
            #pragma unroll
            for (int r = 0; r < 4; ++r) {
                const f16* ar = W2s + (qt * 16 + g4 + r) * 16;
                const f16* hb = &sH1[(et * 16 + m16) * 16];
                float acc = 0.0f;
                for (int h = 0; h < 16; ++h) acc += (float)ar[h] * (float)hb[h];
                hv[r] = (f16)acc;
            }
            *(f16x4*)(sWB + (et * 16 + m16) * SWSTRIDE + (qt * 16 + g4) * 2) = hv;
        }
#endif
    }
    __syncthreads();

    // ---- contraction roles: 32 edges x 8 cols ----
    const int ce = tid & 31;
    const int cj = tid >> 5;
    const float sh0 = sSH[ce * 3 + 0], sh1 = sSH[ce * 3 + 1], sh2 = sSH[ce * 3 + 2];

    // ---- TP1 contraction ----
    {
        float sts = 0.0f, svs = 0.0f, vt0 = 0.0f, vt1 = 0.0f, vt2 = 0.0f;
        #pragma unroll 4
        for (int u = 0; u < 16; ++u) {
            const float4 d = *(const float4*)&sXP[ce * 68 + 4 * u];  // [su,a0,a1,a2]
            const float vd = d.y * sh0 + d.z * sh1 + d.w * sh2;
            f16x4 wv4 = *(const f16x4*)(sWB + ce * SWSTRIDE + ((u * 8 + cj) * 4) * 2);
            const float wss = (float)wv4[0];
            const float wvv = (float)wv4[1];
            const float wsv = (float)wv4[2];
            const float wvs = (float)wv4[3];
            sts += d.x * wss + vd * wvv;
            svs += d.x * wsv;
            vt0 += d.y * wvs;
            vt1 += d.z * wvs;
            vt2 += d.w * wvs;
        }
        float4 stvt;
        stvt.x = sts;
        stvt.y = svs * sh0 + vt0;
        stvt.z = svs * sh1 + vt1;
        stvt.w = svs * sh2 + vt2;
        *(float4*)&sSTVT[ce * 36 + 4 * cj] = stvt;
    }
    __syncthreads();

    // ---- MFMA phase 2: w2 = W4s[512,16] @ H2^T[16,32] -> sW fp16 ----
    {
#if HAVE_MFMA16
        f16x4 bf = *(const f16x4*)&sH2[(et * 16 + m16) * 16 + g4];
        #pragma unroll
        for (int t = 0; t < 16; ++t) {
            const int qt = qh * 16 + t;
            f16x4 af = *(const f16x4*)(W4s + (qt * 16 + m16) * 16 + g4);
            f32x4v acc = (f32x4v){0.0f, 0.0f, 0.0f, 0.0f};
            acc = MFMA16(af, bf, acc);
            f16x4 hv;
            hv[0] = (f16)acc[0]; hv[1] = (f16)acc[1];
            hv[2] = (f16)acc[2]; hv[3] = (f16)acc[3];
            *(f16x4*)(sWB + (et * 16 + m16) * SWSTRIDE + (qt * 16 + g4) * 2) = hv;
        }
#else
        #pragma unroll 2
        for (int t = 0; t < 16; ++t) {
            const int qt = qh * 16 + t;
            f16x4 hv;
            #pragma unroll
            for (int r = 0; r < 4; ++r) {
                const f16* ar = W4s + (qt * 16 + g4 + r) * 16;
                const f16* hb = &sH2[(et * 16 + m16) * 16];
                float acc = 0.0f;
                for (int h = 0; h < 16; ++h) acc += (float)ar[h] * (float)hb[h];
                hv[r] = (f16)acc;
            }
            *(f16x4*)(sWB + (et * 16 + m16) * SWSTRIDE + (qt * 16 + g4) * 2) = hv;
        }
#endif
    }
    __syncthreads();

    // ---- TP2 contraction ----
    float out_ts, out_v0, out_v1, out_v2;
    {
        float scal = 0.0f, gat = 0.0f, csv = 0.0f, vv0 = 0.0f, vv1 = 0.0f, vv2 = 0.0f;
        #pragma unroll 4
        for (int u = 0; u < 8; ++u) {
            const float4 d = *(const float4*)&sSTVT[ce * 36 + 4 * u];
            const float vd = d.y * sh0 + d.z * sh1 + d.w * sh2;
            f16x8 wv8 = *(const f16x8*)(sWB + ce * SWSTRIDE + ((u * 8 + cj) * 8) * 2);
            scal += d.x * (float)wv8[0] + vd * (float)wv8[1];
            gat  += d.x * (float)wv8[2] + vd * (float)wv8[3];
            csv  += d.x * (float)wv8[4];
            const float wCv = (float)wv8[5];
            vv0  += d.y * wCv;
            vv1  += d.z * wCv;
            vv2  += d.w * wCv;
        }
        const float ve0 = csv * sh0 + vv0;
        const float ve1 = csv * sh1 + vv1;
        const float ve2 = csv * sh2 + vv2;
        const float nn = sNRM[ce];
        const float ts = tanh_fast(scal) * nn;
        const float tg = tanh_fast(gat) * nn;
        out_ts = ts;
        out_v0 = ve0 * tg;
        out_v1 = ve1 * tg;
        out_v2 = ve2 * tg;
    }

    if (ATOMIC) {
        if (ce < nvalid) {
            float* ob = dst_buf + (size_t)sDST[ce] * 32;
            atomicAdd(ob + cj,             out_ts);
            atomicAdd(ob + 8 + 3 * cj + 0, out_v0);
            atomicAdd(ob + 8 + 3 * cj + 1, out_v1);
            atomicAdd(ob + 8 + 3 * cj + 2, out_v2);
        }
    } else {
        // stage into sXP (last read 2 barriers ago), then coalesced line store
        float* sOUT = sXP;
        sOUT[ce * 68 + cj]             = out_ts;
        sOUT[ce * 68 + 8 + 3 * cj + 0] = out_v0;
        sOUT[ce * 68 + 8 + 3 * cj + 1] = out_v1;
        sOUT[ce * 68 + 8 + 3 * cj + 2] = out_v2;
        __syncthreads();
        if (e < nvalid) {
            float4 v = *(const float4*)&sOUT[e * 68 + 4 * q];
            *(float4*)&dst_buf[(size_t)sPOS[e] * 32 + 4 * q] = v;
        }
    }
}

extern "C" void kernel_launch(void* const* d_in, const int* in_sizes, int n_in,
                              void* d_out, int out_size, void* d_ws, size_t ws_size,
                              hipStream_t stream) {
    const float* x    = (const float*)d_in[0];
    const int*   esrc = (const int*)  d_in[1];
    const int*   edst = (const int*)  d_in[2];
    const float* evec = (const float*)d_in[3];
    const float* emb  = (const float*)d_in[4];
    const float* nrm  = (const float*)d_in[5];
    const float* W1   = (const float*)d_in[7];
    const float* W2   = (const float*)d_in[8];
    const float* W3   = (const float*)d_in[9];
    const float* W4   = (const float*)d_in[10];
    float* out = (float*)d_out;

    const int E  = in_sizes[1];
    const int NN = out_size / 32;
    const int nbatch = (E + EPB - 1) / EPB;

    size_t o_w2s   = 0;                                   // 512*16*2 = 16384
    size_t o_w4s   = o_w2s + 512 * 16 * 2;                // 16384
    size_t o_cnt   = o_w4s + 512 * 16 * 2;
    size_t o_off   = o_cnt + (size_t)NNP * 4;
    size_t o_rank  = o_off + (size_t)NNP * 4;
    size_t o_eout  = (o_rank + (size_t)E * 4 + 255) & ~(size_t)255;
    size_t need    = o_eout + (size_t)E * 128;

    char* ws = (char*)d_ws;
    f16* W2s = (f16*)(ws + o_w2s);
    f16* W4s = (f16*)(ws + o_w4s);
    int*   counts  = (int*)  (ws + o_cnt);
    int*   offsets = (int*)  (ws + o_off);
    int*   rank    = (int*)  (ws + o_rank);
    float* eout    = (float*)(ws + o_eout);

    const int prep_threads = NNP + 16384;
    prep<<<(prep_threads + 255) / 256, 256, 0, stream>>>(W2, W4, W2s, W4s, counts, NN);

    if (NN <= NNP && ws_size >= need) {
        hist_rank<<<(E + 255) / 256, 256, 0, stream>>>(edst, counts, rank, E);
        scan_offsets<<<1, 1024, 0, stream>>>(counts, offsets, NN);
        eq_nlmp<0><<<nbatch, BLOCK, 0, stream>>>(x, esrc, edst, evec, emb, nrm,
                                                 W1, W3, W2s, W4s, offsets, rank, eout, E);
        gather_out<<<(NN + 7) / 8, 256, 0, stream>>>(eout, offsets, counts, out, NN);
    } else {
        zero_f32<<<(out_size + 255) / 256, 256, 0, stream>>>(out, out_size);
        eq_nlmp<1><<<nbatch, BLOCK, 0, stream>>>(x, esrc, edst, evec, emb, nrm,
                                                 W1, W3, W2s, W4s, nullptr, nullptr, out, E);
    }
}

// Round 10
// 84.597 us; speedup vs baseline: 1.9976x; 1.0823x over previous
//
#include <hip/hip_runtime.h>

// ---------------------------------------------------------------------------
// Fused equivariant NLMP, MI355X — MFMA edition v2.
// Per 32-edge block: w = W2sigma[512,16] @ H^T[16,32] via mfma_f32_16x16x16f16,
// computed in FOUR half-phases (256 sigma rows each) into a half-size LDS
// buffer (stride 520 B = 130 words == 2 mod 32 -> conflict-free), interleaved
// with the matching contraction u-halves. 35.8 KB LDS -> 4 blocks/CU.
// CSR rank placement + streaming gather unchanged.
// ---------------------------------------------------------------------------

#define EPB   32
#define BLOCK 256
#define NNP   10240

#define SQRT3_F      1.7320508075688772f
#define INV_SQRT3_F  0.5773502691896258f
#define INV_SQRT10_F 0.31622776601683794f
#define A1_4         0.044194173824159216f   // (1/sqrt(32)) * (1/4)
#define A2_4         0.0625f                 // (1/sqrt(16)) * (1/4)

#define SWSTRIDE 520   // bytes per edge half-row: 256 f16 + 8B pad; 130 words == 2 mod 32

typedef _Float16 f16;
typedef f16 f16x2 __attribute__((ext_vector_type(2)));
typedef f16 f16x4 __attribute__((ext_vector_type(4)));
typedef f16 f16x8 __attribute__((ext_vector_type(8)));
typedef float f32x4v __attribute__((ext_vector_type(4)));

#if __has_builtin(__builtin_amdgcn_mfma_f32_16x16x16f16)
#define MFMA16(a, b, c) __builtin_amdgcn_mfma_f32_16x16x16f16((a), (b), (c), 0, 0, 0)
#define HAVE_MFMA16 1
#elif __has_builtin(__builtin_amdgcn_mfma_f32_16x16x16_f16)
#define MFMA16(a, b, c) __builtin_amdgcn_mfma_f32_16x16x16_f16((a), (b), (c), 0, 0, 0)
#define HAVE_MFMA16 1
#else
#define HAVE_MFMA16 0
#endif

__global__ void zero_f32(float* __restrict__ p, int n) {
    int i = blockIdx.x * blockDim.x + threadIdx.x;
    if (i < n) p[i] = 0.0f;
}

// fused: zero counts + build sigma-permuted fp16 weight matrices.
// W2s[r][h], r=(u8j)*4+p, q=p*128+(r>>2), p<4           (512x16)
// W4s[r][h], r=(u8j)*8+p, q=p*64+(r>>3), p<6, pad p>=6  (512x16)
__global__ void prep(const float* __restrict__ W2, const float* __restrict__ W4,
                     f16* __restrict__ W2s, f16* __restrict__ W4s,
                     int* __restrict__ counts, int NN) {
    int gid = blockIdx.x * blockDim.x + threadIdx.x;
    if (gid < NN) counts[gid] = 0;
    if (gid >= NNP && gid < NNP + 8192) {
        int idx = gid - NNP;
        int r = idx >> 4, h = idx & 15;
        int p = r & 3;
        int q = p * 128 + (r >> 2);
        float sc = (p == 1) ? (A1_4 * INV_SQRT3_F) : A1_4;
        W2s[r * 16 + h] = (f16)(W2[h * 512 + q] * sc);
    } else if (gid >= NNP + 8192 && gid < NNP + 16384) {
        int idx = gid - NNP - 8192;
        int r = idx >> 4, h = idx & 15;
        int p = r & 7;
        if (p < 6) {
            int q = p * 64 + (r >> 3);
            float sc = (p == 1 || p == 3) ? (A2_4 * INV_SQRT3_F) : A2_4;
            W4s[r * 16 + h] = (f16)(W4[h * 384 + q] * sc);
        } else {
            W4s[r * 16 + h] = (f16)0.0f;
        }
    }
}

__global__ void hist_rank(const int* __restrict__ edst, int* __restrict__ counts,
                          int* __restrict__ rank, int E) {
    int e = blockIdx.x * blockDim.x + threadIdx.x;
    if (e < E) rank[e] = atomicAdd(&counts[edst[e]], 1);
}

// single-block scan, CH elems/thread, two passes, 3 barriers
__global__ void scan_offsets(const int* __restrict__ counts, int* __restrict__ offsets, int nn) {
    __shared__ int wbase[16];
    const int tid = threadIdx.x, lane = tid & 63, w = tid >> 6;
    const int CH = (nn + 1023) >> 10;
    int s = 0;
    for (int k = 0; k < CH; ++k) {
        int i = tid * CH + k;
        if (i < nn) s += counts[i];
    }
    int sc = s;
    #pragma unroll
    for (int off = 1; off < 64; off <<= 1) {
        int t = __shfl_up(sc, off, 64);
        if (lane >= off) sc += t;
    }
    if (lane == 63) wbase[w] = sc;
    __syncthreads();
    if (tid < 16) {
        int v = wbase[tid];
        int p = v;
        #pragma unroll
        for (int off = 1; off < 16; off <<= 1) {
            int t = __shfl_up(p, off, 16);
            if (tid >= off) p += t;
        }
        wbase[tid] = p - v;
    }
    __syncthreads();
    int excl = wbase[w] + sc - s;
    for (int k = 0; k < CH; ++k) {
        int i = tid * CH + k;
        if (i < nn) { offsets[i] = excl; excl += counts[i]; }
    }
}

__global__ void gather_out(const float* __restrict__ eout, const int* __restrict__ offsets,
                           const int* __restrict__ counts, float* __restrict__ out, int nn) {
    const int tid = threadIdx.x;
    const int n = blockIdx.x * 8 + (tid >> 5);
    const int t = tid & 31;
    if (n >= nn) return;
    const int beg = offsets[n];
    const int cnt = counts[n];
    float a0 = 0.0f, a1 = 0.0f, a2 = 0.0f, a3 = 0.0f;
    int k = 0;
    for (; k + 3 < cnt; k += 4) {
        a0 += eout[(size_t)(beg + k) * 32 + t];
        a1 += eout[(size_t)(beg + k + 1) * 32 + t];
        a2 += eout[(size_t)(beg + k + 2) * 32 + t];
        a3 += eout[(size_t)(beg + k + 3) * 32 + t];
    }
    for (; k < cnt; ++k) a0 += eout[(size_t)(beg + k) * 32 + t];
    out[(size_t)n * 32 + t] = (a0 + a1) + (a2 + a3);
}

static __device__ __forceinline__ float tanh_fast(float x) {
    x = fminf(fmaxf(x, -15.0f), 15.0f);
    float e = __expf(2.0f * x);
    return (e - 1.0f) * __builtin_amdgcn_rcpf(e + 1.0f);
}

// ATOMIC=0: write edge line to eout[pos[e]]; ATOMIC=1: atomicAdd into out[N][32]
template <int ATOMIC>
__global__ void __launch_bounds__(BLOCK, 4) eq_nlmp(
    const float* __restrict__ x,        // [N,32]
    const int*   __restrict__ esrc,     // [E]
    const int*   __restrict__ edst,     // [E]
    const float* __restrict__ evec,     // [E,3]
    const float* __restrict__ emb,      // [E,10]
    const float* __restrict__ nrm,      // [E]
    const float* __restrict__ W1,       // [10,16] fp32
    const float* __restrict__ W3,       // [10,16] fp32
    const f16*   __restrict__ W2s,      // sigma layout [512][16]
    const f16*   __restrict__ W4s,      // sigma layout [512][16]
    const int*   __restrict__ offsets,
    const int*   __restrict__ rank,
    float*       __restrict__ dst_buf,
    int E)
{
    __shared__ __align__(16) char  sWraw[EPB * SWSTRIDE];  // half of per-edge w (fp16, sigma order)
    __shared__ float sXP  [EPB * 68];   // per edge u: [su,a0,a1,a2]; reused as sOUT
    __shared__ float sSTVT[EPB * 36];
    __shared__ float sEM  [EPB * 12];
    __shared__ float sSH  [EPB * 3];
    __shared__ f16   sH1  [EPB * 16];   // [e][h] row-major
    __shared__ f16   sH2  [EPB * 16];
    __shared__ float sW1t [16 * 12];
    __shared__ float sW3t [16 * 12];
    __shared__ int   sPOS [EPB];
    __shared__ int   sDST [EPB];
    __shared__ float sNRM [EPB];

    const int tid = threadIdx.x;
    const int e   = tid >> 3;   // prelude/MLP/store role: edge 0..31
    const int q   = tid & 7;

    const int ge0 = blockIdx.x * EPB;
    int ge = ge0 + e;
    const int nvalid = (E - ge0 < EPB) ? (E - ge0) : EPB;
    if (ge >= E) ge = E - 1;

    if (tid < 160) {
        const int row = tid >> 4, hid = tid & 15;
        sW1t[hid * 12 + row] = W1[tid];
        sW3t[hid * 12 + row] = W3[tid];
    }

    // ---- prelude: gather + repack per-edge data ----
    {
        const int src = esrc[ge];
        const int dst = edst[ge];
        const float4* xs4 = (const float4*)(x + (size_t)src * 32);
        const float4* xd4 = (const float4*)(x + (size_t)dst * 32);
        float4 a = xs4[q], bq = xd4[q];
        float av[4] = {a.x, a.y, a.z, a.w};
        float bv[4] = {bq.x, bq.y, bq.z, bq.w};
        #pragma unroll
        for (int m = 0; m < 4; ++m) {
            const int i = 4 * q + m;
            {
                int pos;
                if (i < 8) pos = 4 * i;
                else { int r = i - 8; int u = (r * 2731) >> 13; pos = 4 * u + 1 + (r - 3 * u); }
                sXP[e * 68 + pos] = av[m];
            }
            {
                int pos;
                if (i < 8) pos = 4 * (8 + i);
                else { int r = i - 8; int u = (r * 2731) >> 13; pos = 4 * (8 + u) + 1 + (r - 3 * u); }
                sXP[e * 68 + pos] = bv[m];
            }
        }
        if (q < 5) {
            float2 t = *(const float2*)(emb + (size_t)ge * 10 + 2 * q);
            sEM[e * 12 + 2 * q]     = t.x;
            sEM[e * 12 + 2 * q + 1] = t.y;
        }
        if (q == 0) {
            float vx = evec[(size_t)ge * 3 + 0];
            float vy = evec[(size_t)ge * 3 + 1];
            float vz = evec[(size_t)ge * 3 + 2];
            float rn = sqrtf(vx * vx + vy * vy + vz * vz);
            sSH[e * 3 + 0] = SQRT3_F * vx / rn;
            sSH[e * 3 + 1] = SQRT3_F * vy / rn;
            sSH[e * 3 + 2] = SQRT3_F * vz / rn;
        }
        if (q == 1) sNRM[e] = nrm[ge];
        if (q == 2) {
            if (ATOMIC) sDST[e] = dst;
            else        sPOS[e] = offsets[dst] + rank[ge];
        }
    }
    __syncthreads();

    // ---- MLP1 + MLP2: thread (e,q) computes hid = q, q+8 for both ----
    {
        float2 em0 = *(const float2*)&sEM[e * 12 + 0];
        float2 em1 = *(const float2*)&sEM[e * 12 + 2];
        float2 em2 = *(const float2*)&sEM[e * 12 + 4];
        float2 em3 = *(const float2*)&sEM[e * 12 + 6];
        float2 em4 = *(const float2*)&sEM[e * 12 + 8];
        #pragma unroll
        for (int t = 0; t < 2; ++t) {
            const int hid = q + 8 * t;
            {
                const float4 wa = *(const float4*)&sW1t[hid * 12 + 0];
                const float4 wb = *(const float4*)&sW1t[hid * 12 + 4];
                const float2 wc = *(const float2*)&sW1t[hid * 12 + 8];
                float acc = em0.x*wa.x + em0.y*wa.y + em1.x*wa.z + em1.y*wa.w
                          + em2.x*wb.x + em2.y*wb.y + em3.x*wb.z + em3.y*wb.w
                          + em4.x*wc.x + em4.y*wc.y;
                sH1[e * 16 + hid] = (f16)fmaxf(acc * INV_SQRT10_F, 0.0f);
            }
            {
                const float4 wa = *(const float4*)&sW3t[hid * 12 + 0];
                const float4 wb = *(const float4*)&sW3t[hid * 12 + 4];
                const float2 wc = *(const float2*)&sW3t[hid * 12 + 8];
                float acc = em0.x*wa.x + em0.y*wa.y + em1.x*wa.z + em1.y*wa.w
                          + em2.x*wb.x + em2.y*wb.y + em3.x*wb.z + em3.y*wb.w
                          + em4.x*wc.x + em4.y*wc.y;
                sH2[e * 16 + hid] = (f16)fmaxf(acc * INV_SQRT10_F, 0.0f);
            }
        }
    }
    __syncthreads();

    // ---- MFMA roles ----
    const int l   = tid & 63;
    const int wv  = tid >> 6;     // wave 0..3
    const int et  = wv & 1;       // edge-tile 0..1
    const int qh  = wv >> 1;      // qt-half-within-phase 0..1
    const int m16 = l & 15;
    const int g4  = (l >> 4) << 2;
    char* sWB = sWraw;

    // contraction roles
    const int ce = tid & 31;
    const int cj = tid >> 5;
    const float sh0 = sSH[ce * 3 + 0], sh1 = sSH[ce * 3 + 1], sh2 = sSH[ce * 3 + 2];

    // One MFMA half-phase: computes 256 sigma rows (qtb..qtb+15 of 16 each)
    // into sWB. Each thread: 8 MFMAs (qh picks which 8 of the 16 qt rows).
#if HAVE_MFMA16
#define MFMA_PHASE(Ws, sH, qtb)                                                   \
    {                                                                             \
        f16x4 bf = *(const f16x4*)&(sH)[(et * 16 + m16) * 16 + g4];               \
        _Pragma("unroll")                                                         \
        for (int t = 0; t < 8; ++t) {                                             \
            const int lr = qh * 8 + t;                                            \
            const int qt = (qtb) + lr;                                            \
            f16x4 af = *(const f16x4*)((Ws) + (qt * 16 + m16) * 16 + g4);         \
            f32x4v acc = (f32x4v){0.0f, 0.0f, 0.0f, 0.0f};                        \
            acc = MFMA16(af, bf, acc);                                            \
            f16x4 hv;                                                             \
            hv[0] = (f16)acc[0]; hv[1] = (f16)acc[1];                             \
            hv[2] = (f16)acc[2]; hv[3] = (f16)acc[3];                             \
            *(f16x4*)(sWB + (et * 16 + m16) * SWSTRIDE + (lr * 16 + g4) * 2) = hv;\
        }                                                                         \
    }
#else
#define MFMA_PHASE(Ws, sH, qtb)                                                   \
    {                                                                             \
        _Pragma("unroll 2")                                                       \
        for (int t = 0; t < 8; ++t) {                                             \
            const int lr = qh * 8 + t;                                            \
            const int qt = (qtb) + lr;                                            \
            f16x4 hv;                                                             \
            _Pragma("unroll")                                                     \
            for (int r = 0; r < 4; ++r) {                                         \
                const f16* ar = (Ws) + (qt * 16 + g4 + r) * 16;                   \
                const f16* hb = &(sH)[(et * 16 + m16) * 16];                      \
                float acc = 0.0f;                                                 \
                for (int h = 0; h < 16; ++h) acc += (float)ar[h] * (float)hb[h];  \
                hv[r] = (f16)acc;                                                 \
            }                                                                     \
            *(f16x4*)(sWB + (et * 16 + m16) * SWSTRIDE + (lr * 16 + g4) * 2) = hv;\
        }                                                                         \
    }
#endif

    float sts = 0.0f, svs = 0.0f, vt0 = 0.0f, vt1 = 0.0f, vt2 = 0.0f;

    // ---- TP1 half A: sigma rows 0..255 (u = 0..7) ----
    MFMA_PHASE(W2s, sH1, 0)
    __syncthreads();
    #pragma unroll 4
    for (int u = 0; u < 8; ++u) {
        const float4 d = *(const float4*)&sXP[ce * 68 + 4 * u];
        const float vd = d.y * sh0 + d.z * sh1 + d.w * sh2;
        f16x4 wv4 = *(const f16x4*)(sWB + ce * SWSTRIDE + (u * 8 + cj) * 8);
        sts += d.x * (float)wv4[0] + vd * (float)wv4[1];
        svs += d.x * (float)wv4[2];
        vt0 += d.y * (float)wv4[3];
        vt1 += d.z * (float)wv4[3];
        vt2 += d.w * (float)wv4[3];
    }
    __syncthreads();

    // ---- TP1 half B: sigma rows 256..511 (u = 8..15) ----
    MFMA_PHASE(W2s, sH1, 16)
    __syncthreads();
    #pragma unroll 4
    for (int u = 8; u < 16; ++u) {
        const float4 d = *(const float4*)&sXP[ce * 68 + 4 * u];
        const float vd = d.y * sh0 + d.z * sh1 + d.w * sh2;
        f16x4 wv4 = *(const f16x4*)(sWB + ce * SWSTRIDE + ((u - 8) * 8 + cj) * 8);
        sts += d.x * (float)wv4[0] + vd * (float)wv4[1];
        svs += d.x * (float)wv4[2];
        vt0 += d.y * (float)wv4[3];
        vt1 += d.z * (float)wv4[3];
        vt2 += d.w * (float)wv4[3];
    }
    {
        float4 stvt;
        stvt.x = sts;
        stvt.y = svs * sh0 + vt0;
        stvt.z = svs * sh1 + vt1;
        stvt.w = svs * sh2 + vt2;
        *(float4*)&sSTVT[ce * 36 + 4 * cj] = stvt;
    }
    __syncthreads();

    float scal = 0.0f, gat = 0.0f, csv = 0.0f, vv0 = 0.0f, vv1 = 0.0f, vv2 = 0.0f;

    // ---- TP2 half A: sigma rows 0..255 (u = 0..3) ----
    MFMA_PHASE(W4s, sH2, 0)
    __syncthreads();
    #pragma unroll
    for (int u = 0; u < 4; ++u) {
        const float4 d = *(const float4*)&sSTVT[ce * 36 + 4 * u];
        const float vd = d.y * sh0 + d.z * sh1 + d.w * sh2;
        const char* base = sWB + ce * SWSTRIDE + (u * 8 + cj) * 16;
        f16x4 wa4 = *(const f16x4*)(base);
        f16x4 wb4 = *(const f16x4*)(base + 8);
        scal += d.x * (float)wa4[0] + vd * (float)wa4[1];
        gat  += d.x * (float)wa4[2] + vd * (float)wa4[3];
        csv  += d.x * (float)wb4[0];
        const float wCv = (float)wb4[1];
        vv0  += d.y * wCv;
        vv1  += d.z * wCv;
        vv2  += d.w * wCv;
    }
    __syncthreads();

    // ---- TP2 half B: sigma rows 256..511 (u = 4..7) ----
    MFMA_PHASE(W4s, sH2, 16)
    __syncthreads();
    #pragma unroll
    for (int u = 4; u < 8; ++u) {
        const float4 d = *(const float4*)&sSTVT[ce * 36 + 4 * u];
        const float vd = d.y * sh0 + d.z * sh1 + d.w * sh2;
        const char* base = sWB + ce * SWSTRIDE + ((u - 4) * 8 + cj) * 16;
        f16x4 wa4 = *(const f16x4*)(base);
        f16x4 wb4 = *(const f16x4*)(base + 8);
        scal += d.x * (float)wa4[0] + vd * (float)wa4[1];
        gat  += d.x * (float)wa4[2] + vd * (float)wa4[3];
        csv  += d.x * (float)wb4[0];
        const float wCv = (float)wb4[1];
        vv0  += d.y * wCv;
        vv1  += d.z * wCv;
        vv2  += d.w * wCv;
    }

    const float ve0 = csv * sh0 + vv0;
    const float ve1 = csv * sh1 + vv1;
    const float ve2 = csv * sh2 + vv2;
    const float nn = sNRM[ce];
    const float out_ts = tanh_fast(scal) * nn;
    const float tg     = tanh_fast(gat) * nn;
    const float out_v0 = ve0 * tg;
    const float out_v1 = ve1 * tg;
    const float out_v2 = ve2 * tg;

    if (ATOMIC) {
        if (ce < nvalid) {
            float* ob = dst_buf + (size_t)sDST[ce] * 32;
            atomicAdd(ob + cj,             out_ts);
            atomicAdd(ob + 8 + 3 * cj + 0, out_v0);
            atomicAdd(ob + 8 + 3 * cj + 1, out_v1);
            atomicAdd(ob + 8 + 3 * cj + 2, out_v2);
        }
    } else {
        // stage into sXP (last read several barriers ago), coalesced line store
        __syncthreads();
        float* sOUT = sXP;
        sOUT[ce * 68 + cj]             = out_ts;
        sOUT[ce * 68 + 8 + 3 * cj + 0] = out_v0;
        sOUT[ce * 68 + 8 + 3 * cj + 1] = out_v1;
        sOUT[ce * 68 + 8 + 3 * cj + 2] = out_v2;
        __syncthreads();
        if (e < nvalid) {
            float4 v = *(const float4*)&sOUT[e * 68 + 4 * q];
            *(float4*)&dst_buf[(size_t)sPOS[e] * 32 + 4 * q] = v;
        }
    }
}

extern "C" void kernel_launch(void* const* d_in, const int* in_sizes, int n_in,
                              void* d_out, int out_size, void* d_ws, size_t ws_size,
                              hipStream_t stream) {
    const float* x    = (const float*)d_in[0];
    const int*   esrc = (const int*)  d_in[1];
    const int*   edst = (const int*)  d_in[2];
    const float* evec = (const float*)d_in[3];
    const float* emb  = (const float*)d_in[4];
    const float* nrm  = (const float*)d_in[5];
    const float* W1   = (const float*)d_in[7];
    const float* W3   = (const float*)d_in[9];
    const float* W2   = (const float*)d_in[8];
    const float* W4   = (const float*)d_in[10];
    float* out = (float*)d_out;

    const int E  = in_sizes[1];
    const int NN = out_size / 32;
    const int nbatch = (E + EPB - 1) / EPB;

    size_t o_w2s   = 0;                                   // 512*16*2 = 16384
    size_t o_w4s   = o_w2s + 512 * 16 * 2;                // 16384
    size_t o_cnt   = o_w4s + 512 * 16 * 2;
    size_t o_off   = o_cnt + (size_t)NNP * 4;
    size_t o_rank  = o_off + (size_t)NNP * 4;
    size_t o_eout  = (o_rank + (size_t)E * 4 + 255) & ~(size_t)255;
    size_t need    = o_eout + (size_t)E * 128;

    char* ws = (char*)d_ws;
    f16* W2s = (f16*)(ws + o_w2s);
    f16* W4s = (f16*)(ws + o_w4s);
    int*   counts  = (int*)  (ws + o_cnt);
    int*   offsets = (int*)  (ws + o_off);
    int*   rank    = (int*)  (ws + o_rank);
    float* eout    = (float*)(ws + o_eout);

    const int prep_threads = NNP + 16384;
    prep<<<(prep_threads + 255) / 256, 256, 0, stream>>>(W2, W4, W2s, W4s, counts, NN);

    if (NN <= NNP && ws_size >= need) {
        hist_rank<<<(E + 255) / 256, 256, 0, stream>>>(edst, counts, rank, E);
        scan_offsets<<<1, 1024, 0, stream>>>(counts, offsets, NN);
        eq_nlmp<0><<<nbatch, BLOCK, 0, stream>>>(x, esrc, edst, evec, emb, nrm,
                                                 W1, W3, W2s, W4s, offsets, rank, eout, E);
        gather_out<<<(NN + 7) / 8, 256, 0, stream>>>(eout, offsets, counts, out, NN);
    } else {
        zero_f32<<<(out_size + 255) / 256, 256, 0, stream>>>(out, out_size);
        eq_nlmp<1><<<nbatch, BLOCK, 0, stream>>>(x, esrc, edst, evec, emb, nrm,
                                                 W1, W3, W2s, W4s, nullptr, nullptr, out, E);
    }
}

// Round 12
// 76.471 us; speedup vs baseline: 2.2099x; 1.1063x over previous
//
#include <hip/hip_runtime.h>

// ---------------------------------------------------------------------------
// Fused equivariant NLMP, MI355X — MFMA register-direct edition (v2, host-fix).
// Per 64-edge block, 4 waves; wave owns 16 edges (MFMA col = lane&15 = edge).
// sigma-permuted weights make each MFMA C-fragment = [path p, u=g4..g4+3] for
// one output column j -> contraction is in-register FMAs + 2-round shfl_xor
// reduce over u-quarters. No weight LDS round-trip; 2 barriers total.
// x kept f32 in LDS for accuracy. CSR rank placement + streaming gather.
// ---------------------------------------------------------------------------

#define EPB   64
#define BLOCK 256
#define NNP   10240

#define SQRT3_F      1.7320508075688772f
#define INV_SQRT3_F  0.5773502691896258f
#define INV_SQRT10_F 0.31622776601683794f
#define A1_4         0.044194173824159216f   // (1/sqrt(32)) * (1/4)
#define A2_4         0.0625f                 // (1/sqrt(16)) * (1/4)

typedef _Float16 f16;
typedef f16 f16x4 __attribute__((ext_vector_type(4)));
typedef float f32x4v __attribute__((ext_vector_type(4)));

#if defined(__HIP_DEVICE_COMPILE__)
#  if __has_builtin(__builtin_amdgcn_mfma_f32_16x16x16f16)
#    define MFMA16(a, b, c) __builtin_amdgcn_mfma_f32_16x16x16f16((a), (b), (c), 0, 0, 0)
#  else
#    define MFMA16(a, b, c) __builtin_amdgcn_mfma_f32_16x16x16_f16((a), (b), (c), 0, 0, 0)
#  endif
#else
#  define MFMA16(a, b, c) (c)   /* host pass: parsed, never executed */
#endif

__global__ void zero_f32(float* __restrict__ p, int n) {
    int i = blockIdx.x * blockDim.x + threadIdx.x;
    if (i < n) p[i] = 0.0f;
}

// fused: zero counts + build sigma-permuted fp16 weights.
// W2s row r: j=r>>6, p=(r>>4)&3, u=r&15; q = p*128+u*8+j   (all 512 rows)
// W4s row r: j=r>>6, p=(r>>3)&7, u=r&7;  q = p*64+u*8+j if p<6 (p>=6 zero pad)
__global__ void prep(const float* __restrict__ W2, const float* __restrict__ W4,
                     f16* __restrict__ W2s, f16* __restrict__ W4s,
                     int* __restrict__ counts, int NN) {
    int gid = blockIdx.x * blockDim.x + threadIdx.x;
    if (gid < NN) counts[gid] = 0;
    if (gid >= NNP && gid < NNP + 8192) {
        int idx = gid - NNP;
        int r = idx >> 4, h = idx & 15;
        int j = r >> 6, p = (r >> 4) & 3, u = r & 15;
        int q = p * 128 + u * 8 + j;
        float sc = (p == 1) ? (A1_4 * INV_SQRT3_F) : A1_4;
        W2s[r * 16 + h] = (f16)(W2[h * 512 + q] * sc);
    } else if (gid >= NNP + 8192 && gid < NNP + 16384) {
        int idx = gid - NNP - 8192;
        int r = idx >> 4, h = idx & 15;
        int j = r >> 6, p = (r >> 3) & 7, u = r & 7;
        if (p < 6) {
            int q = p * 64 + u * 8 + j;
            float sc = (p == 1 || p == 3) ? (A2_4 * INV_SQRT3_F) : A2_4;
            W4s[r * 16 + h] = (f16)(W4[h * 384 + q] * sc);
        } else {
            W4s[r * 16 + h] = (f16)0.0f;   // never read
        }
    }
}

__global__ void hist_rank(const int* __restrict__ edst, int* __restrict__ counts,
                          int* __restrict__ rank, int E) {
    int e = blockIdx.x * blockDim.x + threadIdx.x;
    if (e < E) rank[e] = atomicAdd(&counts[edst[e]], 1);
}

// single-block scan, CH elems/thread, two passes, 3 barriers
__global__ void scan_offsets(const int* __restrict__ counts, int* __restrict__ offsets, int nn) {
    __shared__ int wbase[16];
    const int tid = threadIdx.x, lane = tid & 63, w = tid >> 6;
    const int CH = (nn + 1023) >> 10;
    int s = 0;
    for (int k = 0; k < CH; ++k) {
        int i = tid * CH + k;
        if (i < nn) s += counts[i];
    }
    int sc = s;
    #pragma unroll
    for (int off = 1; off < 64; off <<= 1) {
        int t = __shfl_up(sc, off, 64);
        if (lane >= off) sc += t;
    }
    if (lane == 63) wbase[w] = sc;
    __syncthreads();
    if (tid < 16) {
        int v = wbase[tid];
        int p = v;
        #pragma unroll
        for (int off = 1; off < 16; off <<= 1) {
            int t = __shfl_up(p, off, 16);
            if (tid >= off) p += t;
        }
        wbase[tid] = p - v;
    }
    __syncthreads();
    int excl = wbase[w] + sc - s;
    for (int k = 0; k < CH; ++k) {
        int i = tid * CH + k;
        if (i < nn) { offsets[i] = excl; excl += counts[i]; }
    }
}

__global__ void gather_out(const float* __restrict__ eout, const int* __restrict__ offsets,
                           const int* __restrict__ counts, float* __restrict__ out, int nn) {
    const int tid = threadIdx.x;
    const int n = blockIdx.x * 8 + (tid >> 5);
    const int t = tid & 31;
    if (n >= nn) return;
    const int beg = offsets[n];
    const int cnt = counts[n];
    float a0 = 0.0f, a1 = 0.0f, a2 = 0.0f, a3 = 0.0f;
    int k = 0;
    for (; k + 3 < cnt; k += 4) {
        a0 += eout[(size_t)(beg + k) * 32 + t];
        a1 += eout[(size_t)(beg + k + 1) * 32 + t];
        a2 += eout[(size_t)(beg + k + 2) * 32 + t];
        a3 += eout[(size_t)(beg + k + 3) * 32 + t];
    }
    for (; k < cnt; ++k) a0 += eout[(size_t)(beg + k) * 32 + t];
    out[(size_t)n * 32 + t] = (a0 + a1) + (a2 + a3);
}

static __device__ __forceinline__ float tanh_fast(float x) {
    x = fminf(fmaxf(x, -15.0f), 15.0f);
    float e = __expf(2.0f * x);
    return (e - 1.0f) * __builtin_amdgcn_rcpf(e + 1.0f);
}

#define BFLY(v) { v += __shfl_xor(v, 16); v += __shfl_xor(v, 32); }

// ATOMIC=0: write edge line to eout[pos[e]]; ATOMIC=1: atomicAdd into out[N][32]
template <int ATOMIC>
__global__ void __launch_bounds__(BLOCK, 4) eq_nlmp(
    const float* __restrict__ x,        // [N,32]
    const int*   __restrict__ esrc,     // [E]
    const int*   __restrict__ edst,     // [E]
    const float* __restrict__ evec,     // [E,3]
    const float* __restrict__ emb,      // [E,10]
    const float* __restrict__ nrm,      // [E]
    const float* __restrict__ W1,       // [10,16] fp32
    const float* __restrict__ W3,       // [10,16] fp32
    const f16*   __restrict__ W2s,      // sigma layout [512][16]
    const f16*   __restrict__ W4s,      // sigma layout [512][16]
    const int*   __restrict__ offsets,
    const int*   __restrict__ rank,
    float*       __restrict__ dst_buf,
    int E)
{
    __shared__ float sXP [EPB * 68];    // per edge u: f32x4 [su,a0,a1,a2], stride 68 f32
    __shared__ float sSTVT[EPB * 36];   // TP1 out [st,vt0,vt1,vt2] per (e,u); reused as sOUT
    __shared__ float sEM [EPB * 12];
    __shared__ float sSH [EPB * 4];
    __shared__ f16   sH1 [EPB * 16];
    __shared__ f16   sH2 [EPB * 16];
    __shared__ float sW1t[16 * 12];
    __shared__ float sW3t[16 * 12];
    __shared__ int   sPOS[EPB];
    __shared__ int   sDST[EPB];
    __shared__ float sNRM[EPB];

    const int tid = threadIdx.x;
    const int ge0 = blockIdx.x * EPB;
    const int nvalid = (E - ge0 < EPB) ? (E - ge0) : EPB;

    if (tid < 160) {
        const int row = tid >> 4, hid = tid & 15;
        sW1t[hid * 12 + row] = W1[tid];
        sW3t[hid * 12 + row] = W3[tid];
    }

    const int e = tid >> 2;   // edge 0..63 (prelude/MLP role)
    const int c = tid & 3;
    {
        int ge = ge0 + e; if (ge >= E) ge = E - 1;
        const int src = esrc[ge];
        const int dst = edst[ge];
        const float4* xs4 = (const float4*)(x + (size_t)src * 32);
        const float4* xd4 = (const float4*)(x + (size_t)dst * 32);
        float4 A0 = xs4[c], A1 = xs4[c + 4], B0 = xd4[c], B1 = xd4[c + 4];
        const float* a0p = (const float*)&A0;
        const float* a1p = (const float*)&A1;
        const float* b0p = (const float*)&B0;
        const float* b1p = (const float*)&B1;
        float* xp = &sXP[e * 68];
        #pragma unroll
        for (int m = 0; m < 4; ++m) {
            const int i = 4 * c + m;
            {   // xs element i
                int pos;
                if (i < 8) pos = 4 * i;
                else { int r = i - 8; int u = (r * 2731) >> 13; pos = 4 * u + 1 + (r - 3 * u); }
                xp[pos] = a0p[m];
            }
            {   // xs element i+16 (always vector part)
                int r = i + 8; int u = (r * 2731) >> 13;
                xp[4 * u + 1 + (r - 3 * u)] = a1p[m];
            }
            {   // xd element i
                int pos;
                if (i < 8) pos = 32 + 4 * i;
                else { int r = i - 8; int u = (r * 2731) >> 13; pos = 32 + 4 * u + 1 + (r - 3 * u); }
                xp[pos] = b0p[m];
            }
            {   // xd element i+16
                int r = i + 8; int u = (r * 2731) >> 13;
                xp[32 + 4 * u + 1 + (r - 3 * u)] = b1p[m];
            }
        }
        float2 t = *(const float2*)(emb + (size_t)ge * 10 + 2 * c);
        sEM[e * 12 + 2 * c]     = t.x;
        sEM[e * 12 + 2 * c + 1] = t.y;
        if (c == 0) {
            float2 t2 = *(const float2*)(emb + (size_t)ge * 10 + 8);
            sEM[e * 12 + 8] = t2.x;
            sEM[e * 12 + 9] = t2.y;
        } else if (c == 1) {
            float vx = evec[(size_t)ge * 3 + 0];
            float vy = evec[(size_t)ge * 3 + 1];
            float vz = evec[(size_t)ge * 3 + 2];
            float rn = sqrtf(vx * vx + vy * vy + vz * vz);
            sSH[e * 4 + 0] = SQRT3_F * vx / rn;
            sSH[e * 4 + 1] = SQRT3_F * vy / rn;
            sSH[e * 4 + 2] = SQRT3_F * vz / rn;
            sSH[e * 4 + 3] = 0.0f;
        } else if (c == 2) {
            sNRM[e] = nrm[ge];
        } else {
            if (ATOMIC) sDST[e] = dst;
            else        sPOS[e] = offsets[dst] + rank[ge];
        }
    }
    __syncthreads();   // B1: sW1t/sW3t cross-wave visibility

    // ---- MLP1 + MLP2: thread (e,c) computes hid = c+4k for both ----
    // (edge e is handled by threads of the same wave that later consume it)
    {
        float2 em0 = *(const float2*)&sEM[e * 12 + 0];
        float2 em1 = *(const float2*)&sEM[e * 12 + 2];
        float2 em2 = *(const float2*)&sEM[e * 12 + 4];
        float2 em3 = *(const float2*)&sEM[e * 12 + 6];
        float2 em4 = *(const float2*)&sEM[e * 12 + 8];
        #pragma unroll
        for (int k = 0; k < 4; ++k) {
            const int hid = c + 4 * k;
            {
                const float4 wa = *(const float4*)&sW1t[hid * 12 + 0];
                const float4 wb = *(const float4*)&sW1t[hid * 12 + 4];
                const float2 wc = *(const float2*)&sW1t[hid * 12 + 8];
                float acc = em0.x*wa.x + em0.y*wa.y + em1.x*wa.z + em1.y*wa.w
                          + em2.x*wb.x + em2.y*wb.y + em3.x*wb.z + em3.y*wb.w
                          + em4.x*wc.x + em4.y*wc.y;
                sH1[e * 16 + hid] = (f16)fmaxf(acc * INV_SQRT10_F, 0.0f);
            }
            {
                const float4 wa = *(const float4*)&sW3t[hid * 12 + 0];
                const float4 wb = *(const float4*)&sW3t[hid * 12 + 4];
                const float2 wc = *(const float2*)&sW3t[hid * 12 + 8];
                float acc = em0.x*wa.x + em0.y*wa.y + em1.x*wa.z + em1.y*wa.w
                          + em2.x*wb.x + em2.y*wb.y + em3.x*wb.z + em3.y*wb.w
                          + em4.x*wc.x + em4.y*wc.y;
                sH2[e * 16 + hid] = (f16)fmaxf(acc * INV_SQRT10_F, 0.0f);
            }
        }
    }
    // no barrier: all further LDS deps are same-wave (per-wave in-order LDS)

    // ---- contraction roles: wave owns 16 edges; lane = (edge m16, quarter qid) ----
    const int l   = tid & 63;
    const int m16 = l & 15;
    const int g4  = (l >> 4) << 2;
    const int qid = l >> 4;
    const int le  = ((tid >> 6) << 4) + m16;   // local edge (same wave wrote it)

    const float4 shv = *(const float4*)&sSH[le * 4];
    const float  nnv = sNRM[le];

    // TP1 d-preload: u = g4..g4+3 (fixed per lane)
    float4 d[4]; float vd[4];
    #pragma unroll
    for (int r = 0; r < 4; ++r) {
        d[r] = *(const float4*)&sXP[le * 68 + 4 * (g4 + r)];
        vd[r] = d[r].y * shv.x + d[r].z * shv.y + d[r].w * shv.z;
    }
    const f16x4 bf = *(const f16x4*)&sH1[le * 16 + g4];
    const f16* __restrict__ w2l = W2s + m16 * 16 + g4;
    const f32x4v zz = (f32x4v){0.0f, 0.0f, 0.0f, 0.0f};

    // ---- TP1: 4 MFMAs per j (p = 0..3), butterfly over u-quarters ----
    #pragma unroll 2
    for (int j = 0; j < 8; ++j) {
        float sts, svs, vt0, vt1, vt2;
        {
            f16x4 af = *(const f16x4*)(w2l + (4 * j + 0) * 256);
            f32x4v a = MFMA16(af, bf, zz);
            sts = d[0].x*a[0] + d[1].x*a[1] + d[2].x*a[2] + d[3].x*a[3];
        }
        {
            f16x4 af = *(const f16x4*)(w2l + (4 * j + 1) * 256);
            f32x4v a = MFMA16(af, bf, zz);
            sts += vd[0]*a[0] + vd[1]*a[1] + vd[2]*a[2] + vd[3]*a[3];
        }
        {
            f16x4 af = *(const f16x4*)(w2l + (4 * j + 2) * 256);
            f32x4v a = MFMA16(af, bf, zz);
            svs = d[0].x*a[0] + d[1].x*a[1] + d[2].x*a[2] + d[3].x*a[3];
        }
        {
            f16x4 af = *(const f16x4*)(w2l + (4 * j + 3) * 256);
            f32x4v a = MFMA16(af, bf, zz);
            vt0 = d[0].y*a[0] + d[1].y*a[1] + d[2].y*a[2] + d[3].y*a[3];
            vt1 = d[0].z*a[0] + d[1].z*a[1] + d[2].z*a[2] + d[3].z*a[3];
            vt2 = d[0].w*a[0] + d[1].w*a[1] + d[2].w*a[2] + d[3].w*a[3];
        }
        BFLY(sts) BFLY(svs) BFLY(vt0) BFLY(vt1) BFLY(vt2)
        if (l < 16) {
            float4 o;
            o.x = sts;
            o.y = svs * shv.x + vt0;
            o.z = svs * shv.y + vt1;
            o.w = svs * shv.z + vt2;
            *(float4*)&sSTVT[le * 36 + 4 * j] = o;   // TP1's j = TP2's u
        }
    }

    // ---- TP2 preload (same-wave dep on sSTVT) ----
    const int ub = g4 & 4;   // u-base: quarters 0,2 -> u 0..3; 1,3 -> u 4..7
    float fsel[4], cs[4], b0s[4], b1s[4], b2s[4];
    {
        const bool hi = (l >= 32);   // quarters 2,3: odd paths (Avv/Bvv/Cvs rows)
        #pragma unroll
        for (int r = 0; r < 4; ++r) {
            float4 d2 = *(const float4*)&sSTVT[le * 36 + 4 * (ub + r)];
            float v2 = d2.y * shv.x + d2.z * shv.y + d2.w * shv.z;
            fsel[r] = hi ? v2   : d2.x;
            cs[r]   = hi ? 0.0f : d2.x;
            b0s[r]  = hi ? d2.y : 0.0f;
            b1s[r]  = hi ? d2.z : 0.0f;
            b2s[r]  = hi ? d2.w : 0.0f;
        }
    }
    const f16x4 bf2 = *(const f16x4*)&sH2[le * 16 + g4];
    const f16* __restrict__ w4l = W4s + m16 * 16 + g4;
    float outj[8];

    // ---- TP2: 3 MFMAs per j (p-pairs {0,1},{2,3},{4,5}), butterfly ----
    #pragma unroll
    for (int j = 0; j < 8; ++j) {
        float scal, gat, csv, vv0, vv1, vv2;
        {
            f16x4 af = *(const f16x4*)(w4l + (4 * j + 0) * 256);
            f32x4v a = MFMA16(af, bf2, zz);
            scal = fsel[0]*a[0] + fsel[1]*a[1] + fsel[2]*a[2] + fsel[3]*a[3];
        }
        {
            f16x4 af = *(const f16x4*)(w4l + (4 * j + 1) * 256);
            f32x4v a = MFMA16(af, bf2, zz);
            gat = fsel[0]*a[0] + fsel[1]*a[1] + fsel[2]*a[2] + fsel[3]*a[3];
        }
        {
            f16x4 af = *(const f16x4*)(w4l + (4 * j + 2) * 256);
            f32x4v a = MFMA16(af, bf2, zz);
            csv = cs[0]*a[0] + cs[1]*a[1] + cs[2]*a[2] + cs[3]*a[3];
            vv0 = b0s[0]*a[0] + b0s[1]*a[1] + b0s[2]*a[2] + b0s[3]*a[3];
            vv1 = b1s[0]*a[0] + b1s[1]*a[1] + b1s[2]*a[2] + b1s[3]*a[3];
            vv2 = b2s[0]*a[0] + b2s[1]*a[1] + b2s[2]*a[2] + b2s[3]*a[3];
        }
        BFLY(scal) BFLY(gat) BFLY(csv) BFLY(vv0) BFLY(vv1) BFLY(vv2)
        const float ts = tanh_fast(scal) * nnv;
        const float tg = tanh_fast(gat) * nnv;
        const float ve0 = csv * shv.x + vv0;
        const float ve1 = csv * shv.y + vv1;
        const float ve2 = csv * shv.z + vv2;
        outj[j] = (qid == 0) ? ts
                : (qid == 1) ? ve0 * tg
                : (qid == 2) ? ve1 * tg
                             : ve2 * tg;
    }

    if (ATOMIC) {
        if (le < nvalid) {
            float* ob = dst_buf + (size_t)sDST[le] * 32;
            #pragma unroll
            for (int j = 0; j < 8; ++j) {
                const int col = (qid == 0) ? j : (8 + 3 * j + (qid - 1));
                atomicAdd(ob + col, outj[j]);
            }
        }
    } else {
        // stage to sOUT (= sSTVT reuse, own-wave rows only), then coalesced write
        float* sOUT = sSTVT;
        #pragma unroll
        for (int j = 0; j < 8; ++j) {
            const int col = (qid == 0) ? j : (8 + 3 * j + (qid - 1));
            sOUT[le * 36 + col] = outj[j];
        }
        __syncthreads();   // B2: cross-wave before role-remapped global write
        #pragma unroll
        for (int k = 0; k < 2; ++k) {
            const int idx = tid + k * 256;
            const int ee = idx >> 3, q8 = idx & 7;
            if (ee < nvalid) {
                float4 v = *(const float4*)&sOUT[ee * 36 + 4 * q8];
                *(float4*)&dst_buf[(size_t)sPOS[ee] * 32 + 4 * q8] = v;
            }
        }
    }
}

extern "C" void kernel_launch(void* const* d_in, const int* in_sizes, int n_in,
                              void* d_out, int out_size, void* d_ws, size_t ws_size,
                              hipStream_t stream) {
    const float* x    = (const float*)d_in[0];
    const int*   esrc = (const int*)  d_in[1];
    const int*   edst = (const int*)  d_in[2];
    const float* evec = (const float*)d_in[3];
    const float* emb  = (const float*)d_in[4];
    const float* nrm  = (const float*)d_in[5];
    const float* W1   = (const float*)d_in[7];
    const float* W2   = (const float*)d_in[8];
    const float* W3   = (const float*)d_in[9];
    const float* W4   = (const float*)d_in[10];
    float* out = (float*)d_out;

    const int E  = in_sizes[1];
    const int NN = out_size / 32;
    const int nbatch = (E + EPB - 1) / EPB;

    size_t o_w2s   = 0;                                   // 512*16*2 = 16384
    size_t o_w4s   = o_w2s + 512 * 16 * 2;                // 16384
    size_t o_cnt   = o_w4s + 512 * 16 * 2;
    size_t o_off   = o_cnt + (size_t)NNP * 4;
    size_t o_rank  = o_off + (size_t)NNP * 4;
    size_t o_eout  = (o_rank + (size_t)E * 4 + 255) & ~(size_t)255;
    size_t need    = o_eout + (size_t)E * 128;

    char* ws = (char*)d_ws;
    f16* W2s = (f16*)(ws + o_w2s);
    f16* W4s = (f16*)(ws + o_w4s);
    int*   counts  = (int*)  (ws + o_cnt);
    int*   offsets = (int*)  (ws + o_off);
    int*   rank    = (int*)  (ws + o_rank);
    float* eout    = (float*)(ws + o_eout);

    const int prep_threads = NNP + 16384;
    prep<<<(prep_threads + 255) / 256, 256, 0, stream>>>(W2, W4, W2s, W4s, counts, NN);

    if (NN <= NNP && ws_size >= need) {
        hist_rank<<<(E + 255) / 256, 256, 0, stream>>>(edst, counts, rank, E);
        scan_offsets<<<1, 1024, 0, stream>>>(counts, offsets, NN);
        eq_nlmp<0><<<nbatch, BLOCK, 0, stream>>>(x, esrc, edst, evec, emb, nrm,
                                                 W1, W3, W2s, W4s, offsets, rank, eout, E);
        gather_out<<<(NN + 7) / 8, 256, 0, stream>>>(eout, offsets, counts, out, NN);
    } else {
        zero_f32<<<(out_size + 255) / 256, 256, 0, stream>>>(out, out_size);
        eq_nlmp<1><<<nbatch, BLOCK, 0, stream>>>(x, esrc, edst, evec, emb, nrm,
                                                 W1, W3, W2s, W4s, nullptr, nullptr, out, E);
    }
}

// Round 15
// 72.466 us; speedup vs baseline: 2.3320x; 1.0553x over previous
//
#include <hip/hip_runtime.h>

// ---------------------------------------------------------------------------
// Fused equivariant NLMP, MI355X — MFMA register-direct edition (v5).
// Per 64-edge block, 4 waves; wave owns 16 edges (MFMA col = lane&15 = edge).
// sigma-permuted weights make each MFMA C-fragment = [path p, u=g4..g4+3] for
// one output column j -> contraction is in-register FMAs + shfl_xor reduce
// over u-quarters (pre-combined linear terms: 144 shuffles vs 176).
// x stored f16 in LDS -> 28.4 KB -> 5 blocks/CU. 2 barriers.
// CSR rank placement + streaming gather.
// ---------------------------------------------------------------------------

#define EPB   64
#define BLOCK 256
#define NNP   10240

#define SQRT3_F      1.7320508075688772f
#define INV_SQRT3_F  0.5773502691896258f
#define INV_SQRT10_F 0.31622776601683794f
#define A1_4         0.044194173824159216f   // (1/sqrt(32)) * (1/4)
#define A2_4         0.0625f                 // (1/sqrt(16)) * (1/4)

typedef _Float16 f16;
typedef f16 f16x4 __attribute__((ext_vector_type(4)));
typedef float f32x4v __attribute__((ext_vector_type(4)));

#if defined(__HIP_DEVICE_COMPILE__)
#  if __has_builtin(__builtin_amdgcn_mfma_f32_16x16x16f16)
#    define MFMA16(a, b, c) __builtin_amdgcn_mfma_f32_16x16x16f16((a), (b), (c), 0, 0, 0)
#  else
#    define MFMA16(a, b, c) __builtin_amdgcn_mfma_f32_16x16x16_f16((a), (b), (c), 0, 0, 0)
#  endif
#else
#  define MFMA16(a, b, c) (c)   /* host pass: parsed, never executed */
#endif

// verified-correct reduce over lanes {l, l^16, l^32, l^48} (r12 baseline).
// NOTE: permlane16/32_swap builtins produced wrong results on this target
// (r13/r14) — do not substitute them.
#define BFLY(v) { v += __shfl_xor(v, 16); v += __shfl_xor(v, 32); }

__global__ void zero_f32(float* __restrict__ p, int n) {
    int i = blockIdx.x * blockDim.x + threadIdx.x;
    if (i < n) p[i] = 0.0f;
}

// fused: zero counts + build sigma-permuted fp16 weights.
// W2s row r: j=r>>6, p=(r>>4)&3, u=r&15; q = p*128+u*8+j   (all 512 rows)
// W4s row r: j=r>>6, p=(r>>3)&7, u=r&7;  q = p*64+u*8+j if p<6 (p>=6 zero pad)
__global__ void prep(const float* __restrict__ W2, const float* __restrict__ W4,
                     f16* __restrict__ W2s, f16* __restrict__ W4s,
                     int* __restrict__ counts, int NN) {
    int gid = blockIdx.x * blockDim.x + threadIdx.x;
    if (gid < NN) counts[gid] = 0;
    if (gid >= NNP && gid < NNP + 8192) {
        int idx = gid - NNP;
        int r = idx >> 4, h = idx & 15;
        int j = r >> 6, p = (r >> 4) & 3, u = r & 15;
        int q = p * 128 + u * 8 + j;
        float sc = (p == 1) ? (A1_4 * INV_SQRT3_F) : A1_4;
        W2s[r * 16 + h] = (f16)(W2[h * 512 + q] * sc);
    } else if (gid >= NNP + 8192 && gid < NNP + 16384) {
        int idx = gid - NNP - 8192;
        int r = idx >> 4, h = idx & 15;
        int j = r >> 6, p = (r >> 3) & 7, u = r & 7;
        if (p < 6) {
            int q = p * 64 + u * 8 + j;
            float sc = (p == 1 || p == 3) ? (A2_4 * INV_SQRT3_F) : A2_4;
            W4s[r * 16 + h] = (f16)(W4[h * 384 + q] * sc);
        } else {
            W4s[r * 16 + h] = (f16)0.0f;   // never read
        }
    }
}

__global__ void hist_rank(const int* __restrict__ edst, int* __restrict__ counts,
                          int* __restrict__ rank, int E) {
    int e = blockIdx.x * blockDim.x + threadIdx.x;
    if (e < E) rank[e] = atomicAdd(&counts[edst[e]], 1);
}

// single-block scan, CH elems/thread, two passes, 3 barriers
__global__ void scan_offsets(const int* __restrict__ counts, int* __restrict__ offsets, int nn) {
    __shared__ int wbase[16];
    const int tid = threadIdx.x, lane = tid & 63, w = tid >> 6;
    const int CH = (nn + 1023) >> 10;
    int s = 0;
    for (int k = 0; k < CH; ++k) {
        int i = tid * CH + k;
        if (i < nn) s += counts[i];
    }
    int sc = s;
    #pragma unroll
    for (int off = 1; off < 64; off <<= 1) {
        int t = __shfl_up(sc, off, 64);
        if (lane >= off) sc += t;
    }
    if (lane == 63) wbase[w] = sc;
    __syncthreads();
    if (tid < 16) {
        int v = wbase[tid];
        int p = v;
        #pragma unroll
        for (int off = 1; off < 16; off <<= 1) {
            int t = __shfl_up(p, off, 16);
            if (tid >= off) p += t;
        }
        wbase[tid] = p - v;
    }
    __syncthreads();
    int excl = wbase[w] + sc - s;
    for (int k = 0; k < CH; ++k) {
        int i = tid * CH + k;
        if (i < nn) { offsets[i] = excl; excl += counts[i]; }
    }
}

__global__ void gather_out(const float* __restrict__ eout, const int* __restrict__ offsets,
                           const int* __restrict__ counts, float* __restrict__ out, int nn) {
    const int tid = threadIdx.x;
    const int n = blockIdx.x * 8 + (tid >> 5);
    const int t = tid & 31;
    if (n >= nn) return;
    const int beg = offsets[n];
    const int cnt = counts[n];
    float a0 = 0.0f, a1 = 0.0f, a2 = 0.0f, a3 = 0.0f;
    int k = 0;
    for (; k + 3 < cnt; k += 4) {
        a0 += eout[(size_t)(beg + k) * 32 + t];
        a1 += eout[(size_t)(beg + k + 1) * 32 + t];
        a2 += eout[(size_t)(beg + k + 2) * 32 + t];
        a3 += eout[(size_t)(beg + k + 3) * 32 + t];
    }
    for (; k < cnt; ++k) a0 += eout[(size_t)(beg + k) * 32 + t];
    out[(size_t)n * 32 + t] = (a0 + a1) + (a2 + a3);
}

static __device__ __forceinline__ float tanh_fast(float x) {
    x = fminf(fmaxf(x, -15.0f), 15.0f);
    float e = __expf(2.0f * x);
    return (e - 1.0f) * __builtin_amdgcn_rcpf(e + 1.0f);
}

// ATOMIC=0: write edge line to eout[pos[e]]; ATOMIC=1: atomicAdd into out[N][32]
template <int ATOMIC>
__global__ void __launch_bounds__(BLOCK, 5) eq_nlmp(
    const float* __restrict__ x,        // [N,32]
    const int*   __restrict__ esrc,     // [E]
    const int*   __restrict__ edst,     // [E]
    const float* __restrict__ evec,     // [E,3]
    const float* __restrict__ emb,      // [E,10]
    const float* __restrict__ nrm,      // [E]
    const float* __restrict__ W1,       // [10,16] fp32
    const float* __restrict__ W3,       // [10,16] fp32
    const f16*   __restrict__ W2s,      // sigma layout [512][16]
    const f16*   __restrict__ W4s,      // sigma layout [512][16]
    const int*   __restrict__ offsets,
    const int*   __restrict__ rank,
    float*       __restrict__ dst_buf,
    int E)
{
    __shared__ f16   sXPh[EPB * 68];    // per edge u: f16x4 [su,a0,a1,a2], stride 68 f16
    __shared__ float sSTVT[EPB * 36];   // TP1 out [st,vt0,vt1,vt2] per (e,u); reused as sOUT
    __shared__ float sEM [EPB * 12];
    __shared__ float sSH [EPB * 4];
    __shared__ f16   sH1 [EPB * 16];
    __shared__ f16   sH2 [EPB * 16];
    __shared__ float sW1t[16 * 12];
    __shared__ float sW3t[16 * 12];
    __shared__ int   sPOS[EPB];
    __shared__ int   sDST[EPB];
    __shared__ float sNRM[EPB];

    const int tid = threadIdx.x;
    const int ge0 = blockIdx.x * EPB;
    const int nvalid = (E - ge0 < EPB) ? (E - ge0) : EPB;

    if (tid < 160) {
        const int row = tid >> 4, hid = tid & 15;
        sW1t[hid * 12 + row] = W1[tid];
        sW3t[hid * 12 + row] = W3[tid];
    }

    const int e = tid >> 2;   // edge 0..63 (prelude/MLP role)
    const int c = tid & 3;
    {
        int ge = ge0 + e; if (ge >= E) ge = E - 1;
        const int src = esrc[ge];
        const int dst = edst[ge];
        const float4* xs4 = (const float4*)(x + (size_t)src * 32);
        const float4* xd4 = (const float4*)(x + (size_t)dst * 32);
        float4 A0 = xs4[c], A1 = xs4[c + 4], B0 = xd4[c], B1 = xd4[c + 4];
        const float* a0p = (const float*)&A0;
        const float* a1p = (const float*)&A1;
        const float* b0p = (const float*)&B0;
        const float* b1p = (const float*)&B1;
        f16* xph = &sXPh[e * 68];
        #pragma unroll
        for (int m = 0; m < 4; ++m) {
            const int i = 4 * c + m;
            {   // xs element i
                int pos;
                if (i < 8) pos = 4 * i;
                else { int r = i - 8; int u = (r * 2731) >> 13; pos = 4 * u + 1 + (r - 3 * u); }
                xph[pos] = (f16)a0p[m];
            }
            {   // xs element i+16 (always vector part)
                int r = i + 8; int u = (r * 2731) >> 13;
                xph[4 * u + 1 + (r - 3 * u)] = (f16)a1p[m];
            }
            {   // xd element i
                int pos;
                if (i < 8) pos = 32 + 4 * i;
                else { int r = i - 8; int u = (r * 2731) >> 13; pos = 32 + 4 * u + 1 + (r - 3 * u); }
                xph[pos] = (f16)b0p[m];
            }
            {   // xd element i+16
                int r = i + 8; int u = (r * 2731) >> 13;
                xph[32 + 4 * u + 1 + (r - 3 * u)] = (f16)b1p[m];
            }
        }
        float2 t = *(const float2*)(emb + (size_t)ge * 10 + 2 * c);
        sEM[e * 12 + 2 * c]     = t.x;
        sEM[e * 12 + 2 * c + 1] = t.y;
        if (c == 0) {
            float2 t2 = *(const float2*)(emb + (size_t)ge * 10 + 8);
            sEM[e * 12 + 8] = t2.x;
            sEM[e * 12 + 9] = t2.y;
        } else if (c == 1) {
            float vx = evec[(size_t)ge * 3 + 0];
            float vy = evec[(size_t)ge * 3 + 1];
            float vz = evec[(size_t)ge * 3 + 2];
            float rn = sqrtf(vx * vx + vy * vy + vz * vz);
            sSH[e * 4 + 0] = SQRT3_F * vx / rn;
            sSH[e * 4 + 1] = SQRT3_F * vy / rn;
            sSH[e * 4 + 2] = SQRT3_F * vz / rn;
            sSH[e * 4 + 3] = 0.0f;
        } else if (c == 2) {
            sNRM[e] = nrm[ge];
        } else {
            if (ATOMIC) sDST[e] = dst;
            else        sPOS[e] = offsets[dst] + rank[ge];
        }
    }
    __syncthreads();   // B1: sW1t/sW3t cross-wave visibility

    // ---- MLP1 + MLP2: thread (e,c) computes hid = c+4k for both ----
    {
        float2 em0 = *(const float2*)&sEM[e * 12 + 0];
        float2 em1 = *(const float2*)&sEM[e * 12 + 2];
        float2 em2 = *(const float2*)&sEM[e * 12 + 4];
        float2 em3 = *(const float2*)&sEM[e * 12 + 6];
        float2 em4 = *(const float2*)&sEM[e * 12 + 8];
        #pragma unroll
        for (int k = 0; k < 4; ++k) {
            const int hid = c + 4 * k;
            {
                const float4 wa = *(const float4*)&sW1t[hid * 12 + 0];
                const float4 wb = *(const float4*)&sW1t[hid * 12 + 4];
                const float2 wc = *(const float2*)&sW1t[hid * 12 + 8];
                float acc = em0.x*wa.x + em0.y*wa.y + em1.x*wa.z + em1.y*wa.w
                          + em2.x*wb.x + em2.y*wb.y + em3.x*wb.z + em3.y*wb.w
                          + em4.x*wc.x + em4.y*wc.y;
                sH1[e * 16 + hid] = (f16)fmaxf(acc * INV_SQRT10_F, 0.0f);
            }
            {
                const float4 wa = *(const float4*)&sW3t[hid * 12 + 0];
                const float4 wb = *(const float4*)&sW3t[hid * 12 + 4];
                const float2 wc = *(const float2*)&sW3t[hid * 12 + 8];
                float acc = em0.x*wa.x + em0.y*wa.y + em1.x*wa.z + em1.y*wa.w
                          + em2.x*wb.x + em2.y*wb.y + em3.x*wb.z + em3.y*wb.w
                          + em4.x*wc.x + em4.y*wc.y;
                sH2[e * 16 + hid] = (f16)fmaxf(acc * INV_SQRT10_F, 0.0f);
            }
        }
    }
    // no barrier: all further LDS deps are same-wave (per-wave in-order LDS)

    // ---- contraction roles: wave owns 16 edges; lane = (edge m16, quarter qid) ----
    const int l   = tid & 63;
    const int m16 = l & 15;
    const int g4  = (l >> 4) << 2;
    const int qid = l >> 4;
    const int le  = ((tid >> 6) << 4) + m16;   // local edge (same wave wrote it)

    const float4 shv = *(const float4*)&sSH[le * 4];
    const float  nnv = sNRM[le];

    // TP1 d-preload: u = g4..g4+3 (fixed per lane), converted f16->f32
    float4 d[4]; float vd[4];
    #pragma unroll
    for (int r = 0; r < 4; ++r) {
        f16x4 t = *(const f16x4*)&sXPh[le * 68 + 4 * (g4 + r)];
        d[r].x = (float)t[0]; d[r].y = (float)t[1];
        d[r].z = (float)t[2]; d[r].w = (float)t[3];
        vd[r] = d[r].y * shv.x + d[r].z * shv.y + d[r].w * shv.z;
    }
    const f16x4 bf = *(const f16x4*)&sH1[le * 16 + g4];
    const f16* __restrict__ w2l = W2s + m16 * 16 + g4;
    const f32x4v zz = (f32x4v){0.0f, 0.0f, 0.0f, 0.0f};

    // ---- TP1: 4 MFMAs per j (p = 0..3); pre-combined partials, 4 reduces/j ----
    #pragma unroll 2
    for (int j = 0; j < 8; ++j) {
        float sts, svs, vt0, vt1, vt2;
        {
            f16x4 af = *(const f16x4*)(w2l + (4 * j + 0) * 256);
            f32x4v a = MFMA16(af, bf, zz);
            sts = d[0].x*a[0] + d[1].x*a[1] + d[2].x*a[2] + d[3].x*a[3];
        }
        {
            f16x4 af = *(const f16x4*)(w2l + (4 * j + 1) * 256);
            f32x4v a = MFMA16(af, bf, zz);
            sts += vd[0]*a[0] + vd[1]*a[1] + vd[2]*a[2] + vd[3]*a[3];
        }
        {
            f16x4 af = *(const f16x4*)(w2l + (4 * j + 2) * 256);
            f32x4v a = MFMA16(af, bf, zz);
            svs = d[0].x*a[0] + d[1].x*a[1] + d[2].x*a[2] + d[3].x*a[3];
        }
        {
            f16x4 af = *(const f16x4*)(w2l + (4 * j + 3) * 256);
            f32x4v a = MFMA16(af, bf, zz);
            vt0 = d[0].y*a[0] + d[1].y*a[1] + d[2].y*a[2] + d[3].y*a[3];
            vt1 = d[0].z*a[0] + d[1].z*a[1] + d[2].z*a[2] + d[3].z*a[3];
            vt2 = d[0].w*a[0] + d[1].w*a[1] + d[2].w*a[2] + d[3].w*a[3];
        }
        // pre-combine (shv uniform across reduce partners) -> 4 reduces not 5
        float oy = svs * shv.x + vt0;
        float oz = svs * shv.y + vt1;
        float ow = svs * shv.z + vt2;
        BFLY(sts) BFLY(oy) BFLY(oz) BFLY(ow)
        if (l < 16) {
            float4 o; o.x = sts; o.y = oy; o.z = oz; o.w = ow;
            *(float4*)&sSTVT[le * 36 + 4 * j] = o;   // TP1's j = TP2's u
        }
    }

    // ---- TP2 preload (same-wave dep on sSTVT); pre-combined c0/c1/c2 ----
    const int ub = g4 & 4;   // u-base: quarters 0,2 -> u 0..3; 1,3 -> u 4..7
    float fsel[4], c0[4], c1[4], c2[4];
    {
        const bool hi = (l >= 32);   // quarters 2,3: odd paths (Avv/Bvv/Cvs rows)
        #pragma unroll
        for (int r = 0; r < 4; ++r) {
            float4 d2 = *(const float4*)&sSTVT[le * 36 + 4 * (ub + r)];
            float v2 = d2.y * shv.x + d2.z * shv.y + d2.w * shv.z;
            fsel[r] = hi ? v2   : d2.x;
            c0[r]   = hi ? d2.y : d2.x * shv.x;
            c1[r]   = hi ? d2.z : d2.x * shv.y;
            c2[r]   = hi ? d2.w : d2.x * shv.z;
        }
    }
    const f16x4 bf2 = *(const f16x4*)&sH2[le * 16 + g4];
    const f16* __restrict__ w4l = W4s + m16 * 16 + g4;
    float outj[8];

    // ---- TP2: 3 MFMAs per j (p-pairs {0,1},{2,3},{4,5}); 5 reduces/j ----
    #pragma unroll
    for (int j = 0; j < 8; ++j) {
        float scal, gat, ve0, ve1, ve2;
        {
            f16x4 af = *(const f16x4*)(w4l + (4 * j + 0) * 256);
            f32x4v a = MFMA16(af, bf2, zz);
            scal = fsel[0]*a[0] + fsel[1]*a[1] + fsel[2]*a[2] + fsel[3]*a[3];
        }
        {
            f16x4 af = *(const f16x4*)(w4l + (4 * j + 1) * 256);
            f32x4v a = MFMA16(af, bf2, zz);
            gat = fsel[0]*a[0] + fsel[1]*a[1] + fsel[2]*a[2] + fsel[3]*a[3];
        }
        {
            f16x4 af = *(const f16x4*)(w4l + (4 * j + 2) * 256);
            f32x4v a = MFMA16(af, bf2, zz);
            ve0 = c0[0]*a[0] + c0[1]*a[1] + c0[2]*a[2] + c0[3]*a[3];
            ve1 = c1[0]*a[0] + c1[1]*a[1] + c1[2]*a[2] + c1[3]*a[3];
            ve2 = c2[0]*a[0] + c2[1]*a[1] + c2[2]*a[2] + c2[3]*a[3];
        }
        BFLY(scal) BFLY(gat) BFLY(ve0) BFLY(ve1) BFLY(ve2)
        const float ts = tanh_fast(scal) * nnv;
        const float tg = tanh_fast(gat) * nnv;
        outj[j] = (qid == 0) ? ts
                : (qid == 1) ? ve0 * tg
                : (qid == 2) ? ve1 * tg
                             : ve2 * tg;
    }

    if (ATOMIC) {
        if (le < nvalid) {
            float* ob = dst_buf + (size_t)sDST[le] * 32;
            #pragma unroll
            for (int j = 0; j < 8; ++j) {
                const int col = (qid == 0) ? j : (8 + 3 * j + (qid - 1));
                atomicAdd(ob + col, outj[j]);
            }
        }
    } else {
        // stage to sOUT (= sSTVT reuse, own-wave rows only), then coalesced write
        float* sOUT = sSTVT;
        #pragma unroll
        for (int j = 0; j < 8; ++j) {
            const int col = (qid == 0) ? j : (8 + 3 * j + (qid - 1));
            sOUT[le * 36 + col] = outj[j];
        }
        __syncthreads();   // B2: cross-wave before role-remapped global write
        #pragma unroll
        for (int k = 0; k < 2; ++k) {
            const int idx = tid + k * 256;
            const int ee = idx >> 3, q8 = idx & 7;
            if (ee < nvalid) {
                float4 v = *(const float4*)&sOUT[ee * 36 + 4 * q8];
                *(float4*)&dst_buf[(size_t)sPOS[ee] * 32 + 4 * q8] = v;
            }
        }
    }
}

extern "C" void kernel_launch(void* const* d_in, const int* in_sizes, int n_in,
                              void* d_out, int out_size, void* d_ws, size_t ws_size,
                              hipStream_t stream) {
    const float* x    = (const float*)d_in[0];
    const int*   esrc = (const int*)  d_in[1];
    const int*   edst = (const int*)  d_in[2];
    const float* evec = (const float*)d_in[3];
    const float* emb  = (const float*)d_in[4];
    const float* nrm  = (const float*)d_in[5];
    const float* W1   = (const float*)d_in[7];
    const float* W2   = (const float*)d_in[8];
    const float* W3   = (const float*)d_in[9];
    const float* W4   = (const float*)d_in[10];
    float* out = (float*)d_out;

    const int E  = in_sizes[1];
    const int NN = out_size / 32;
    const int nbatch = (E + EPB - 1) / EPB;

    size_t o_w2s   = 0;                                   // 512*16*2 = 16384
    size_t o_w4s   = o_w2s + 512 * 16 * 2;                // 16384
    size_t o_cnt   = o_w4s + 512 * 16 * 2;
    size_t o_off   = o_cnt + (size_t)NNP * 4;
    size_t o_rank  = o_off + (size_t)NNP * 4;
    size_t o_eout  = (o_rank + (size_t)E * 4 + 255) & ~(size_t)255;
    size_t need    = o_eout + (size_t)E * 128;

    char* ws = (char*)d_ws;
    f16* W2s = (f16*)(ws + o_w2s);
    f16* W4s = (f16*)(ws + o_w4s);
    int*   counts  = (int*)  (ws + o_cnt);
    int*   offsets = (int*)  (ws + o_off);
    int*   rank    = (int*)  (ws + o_rank);
    float* eout    = (float*)(ws + o_eout);

    const int prep_threads = NNP + 16384;
    prep<<<(prep_threads + 255) / 256, 256, 0, stream>>>(W2, W4, W2s, W4s, counts, NN);

    if (NN <= NNP && ws_size >= need) {
        hist_rank<<<(E + 255) / 256, 256, 0, stream>>>(edst, counts, rank, E);
        scan_offsets<<<1, 1024, 0, stream>>>(counts, offsets, NN);
        eq_nlmp<0><<<nbatch, BLOCK, 0, stream>>>(x, esrc, edst, evec, emb, nrm,
                                                 W1, W3, W2s, W4s, offsets, rank, eout, E);
        gather_out<<<(NN + 7) / 8, 256, 0, stream>>>(eout, offsets, counts, out, NN);
    } else {
        zero_f32<<<(out_size + 255) / 256, 256, 0, stream>>>(out, out_size);
        eq_nlmp<1><<<nbatch, BLOCK, 0, stream>>>(x, esrc, edst, evec, emb, nrm,
                                                 W1, W3, W2s, W4s, nullptr, nullptr, out, E);
    }
}